// Round 2
// baseline (760.099 us; speedup 1.0000x reference)
//
#include <hip/hip_runtime.h>
#include <hip/hip_bf16.h>
#include <stdint.h>

#define B_ 64
#define N_ 1024
#define E_ 16384
#define F_ 128
#define H_ 64
#define T_ 10
#define BN (B_*N_)   // 65536
#define BE (B_*E_)   // 1048576

// sigmoid(z) >= p  <=>  z >= log(p/(1-p))
#define TH_INNER (-0.84729786f)   // logit(0.3)
#define TH_CROSS (-2.1972246f)    // logit(0.1)

// ---- dtype-agnostic loads: bf=1 -> packed bf16, bf=0 -> float32 ----
struct F2v { float a, b; };

__device__ __forceinline__ F2v ld2(const void* p, int pair, int bf) {
    F2v r;
    if (bf) {
        uint32_t u = ((const uint32_t*)p)[pair];
        r.a = __uint_as_float(u << 16);
        r.b = __uint_as_float(u & 0xffff0000u);
    } else {
        float2 v = ((const float2*)p)[pair];
        r.a = v.x; r.b = v.y;
    }
    return r;
}

__device__ __forceinline__ float ld1(const void* p, int i, int bf) {
    if (bf) {
        uint16_t u = ((const uint16_t*)p)[i];
        return __uint_as_float(((uint32_t)u) << 16);
    }
    return ((const float*)p)[i];
}

// ---------------- dtype detection (1 wave) ----------------
// If tokens is bf16: low 16 bits of every u32 word decode to |v| <= 0.22.
// If tokens is fp32: low 16 bits are mantissa noise -> fails w.p. ~0.5/word.
__global__ __launch_bounds__(64) void k_detect(const void* __restrict__ tokens,
                                               int* __restrict__ flag) {
    int l = threadIdx.x;
    uint32_t u = ((const uint32_t*)tokens)[l];
    float lo = __uint_as_float(u << 16);
    int ok = (fabsf(lo) <= 1.0f) ? 1 : 0;   // NaN -> 0
    unsigned long long vote = __ballot(ok);
    if (l == 0) *flag = (vote == ~0ull) ? 1 : 0;
}

// ---------------- in-degree via atomics ----------------
__global__ __launch_bounds__(256) void k_deg(const int* __restrict__ dst,
                                             int* __restrict__ in_deg) {
    int i = blockIdx.x * 256 + threadIdx.x;      // [0, BE)
    int b = i >> 14;                             // E_ = 2^14
    atomicAdd(&in_deg[b * N_ + dst[i]], 1);
}

// ---------------- exclusive scan (single block, 1024 thr x 64 elems) ----------------
__global__ __launch_bounds__(1024) void k_scan(const int* __restrict__ in_deg,
                                               int* __restrict__ offs,
                                               int* __restrict__ cursor) {
    __shared__ int sums[1024];
    int t = threadIdx.x;
    int base = t * 64;
    int s = 0;
    for (int i = 0; i < 64; ++i) s += in_deg[base + i];
    sums[t] = s;
    __syncthreads();
    for (int d = 1; d < 1024; d <<= 1) {
        int v = (t >= d) ? sums[t - d] : 0;
        __syncthreads();
        sums[t] += v;
        __syncthreads();
    }
    int start = (t == 0) ? 0 : sums[t - 1];
    for (int i = 0; i < 64; ++i) {
        int v = in_deg[base + i];
        offs[base + i] = start;
        cursor[base + i] = start;
        start += v;
    }
    if (t == 1023) offs[BN] = start;
}

// ---------------- CSR fill ----------------
__global__ __launch_bounds__(256) void k_fill(const int* __restrict__ src,
                                              const int* __restrict__ dst,
                                              int* __restrict__ cursor,
                                              int* __restrict__ csr) {
    int i = blockIdx.x * 256 + threadIdx.x;
    int b = i >> 14;
    int d = b * N_ + dst[i];
    int p = atomicAdd(&cursor[d], 1);
    csr[p] = b * N_ + src[i];
}

// ---------------- token stream (graph-independent), one block of 64 ----------------
__global__ __launch_bounds__(64) void k_tok(const void* __restrict__ tokens,
                                            const void* __restrict__ W1,
                                            const void* __restrict__ b1,
                                            const void* __restrict__ W2,
                                            const void* __restrict__ b2,
                                            const int* __restrict__ flag,
                                            float* __restrict__ P1,
                                            float* __restrict__ P2,
                                            float* __restrict__ tok_sum) {
    __shared__ float tk[T_ * F_], w1[F_ * H_], w2[H_ * H_];
    __shared__ float Min[T_ * T_], ist[T_], idt[T_], h1s[T_ * H_];
    int bf = *flag;
    int l = threadIdx.x;
    for (int i = l; i < T_ * F_; i += 64) tk[i] = ld1(tokens, i, bf);
    for (int i = l; i < F_ * H_; i += 64) w1[i] = ld1(W1, i, bf);
    for (int i = l; i < H_ * H_; i += 64) w2[i] = ld1(W2, i, bf);
    __syncthreads();
    // M_in (thresholded token-token adjacency)
    for (int p = l; p < T_ * T_; p += 64) {
        int i = p / T_, j = p % T_;
        float s = 0.f;
        for (int f = 0; f < F_; ++f) s += tk[i * F_ + f] * tk[j * F_ + f];
        Min[p] = (s >= TH_INNER) ? 1.f : 0.f;
    }
    __syncthreads();
    if (l < T_) {
        float d = 1.f;
        for (int s = 0; s < T_; ++s) d += Min[s * T_ + l];
        ist[l] = 1.f / sqrtf(d);
        idt[l] = 1.f / d;
    }
    __syncthreads();
    // ht1 = tokens @ W1  (lane = output dim)
    float ht1[T_];
    for (int t = 0; t < T_; ++t) {
        float a = 0.f;
        for (int f = 0; f < F_; ++f) a += tk[t * F_ + f] * w1[f * H_ + l];
        ht1[t] = a;
    }
    float b1f = ld1(b1, l, bf);
    for (int t = 0; t < T_; ++t) {
        float a = ht1[t] * idt[t] + b1f;
        for (int s = 0; s < T_; ++s) a += Min[t * T_ + s] * ist[t] * ist[s] * ht1[s];
        a = (a >= 0.f) ? a : 0.01f * a;          // leaky relu
        h1s[t * H_ + l] = a;
        P1[t * H_ + l] = ist[t] * ht1[t];
    }
    __syncthreads();
    // ht2 = h1 @ W2
    float ht2[T_];
    for (int t = 0; t < T_; ++t) {
        float a = 0.f;
        for (int k = 0; k < H_; ++k) a += h1s[t * H_ + k] * w2[k * H_ + l];
        ht2[t] = a;
        P2[t * H_ + l] = ist[t] * a;
    }
    float b2f = ld1(b2, l, bf);
    float ts = 0.f;
    for (int t = 0; t < T_; ++t) {
        float o = ht2[t] * idt[t] + b2f;
        for (int s = 0; s < T_; ++s) o += Min[t * T_ + s] * ist[t] * ist[s] * ht2[s];
        ts += o;                                  // sum over tokens for pooling
    }
    tok_sum[l] = ts;
}

// ---------------- per-node: cross masks, deg, y1 = (x@W1) * inv_s ----------------
__global__ __launch_bounds__(256) void k_node1(const void* __restrict__ x,
                                               const void* __restrict__ tokens,
                                               const void* __restrict__ W1,
                                               const int* __restrict__ in_deg,
                                               const int* __restrict__ flag,
                                               float* __restrict__ y1,
                                               float* __restrict__ inv_s,
                                               int* __restrict__ maskA) {
    __shared__ float w1[F_ * H_];
    int bf = *flag;
    int tid = threadIdx.x;
    for (int i = tid; i < F_ * H_; i += 256) w1[i] = ld1(W1, i, bf);
    __syncthreads();
    int lane = tid & 63, w = tid >> 6;
    int node = blockIdx.x * 4 + w;
    F2v xv = ld2(x, node * (F_ / 2) + lane, bf);   // features 2*lane, 2*lane+1
    float xa = xv.a, xb = xv.b;
    // cross-prune mask: z_t = tok_t . x_node
    unsigned mask = 0;
#pragma unroll
    for (int t = 0; t < T_; ++t) {
        F2v tv = ld2(tokens, t * (F_ / 2) + lane, bf);
        float p = xa * tv.a + xb * tv.b;
#pragma unroll
        for (int d = 32; d >= 1; d >>= 1) p += __shfl_xor(p, d);
        if (p >= TH_CROSS) mask |= (1u << t);
    }
    float deg = 1.f + (float)in_deg[node] + (float)__popc(mask);
    float is = 1.f / sqrtf(deg);
    if (lane == 0) { inv_s[node] = is; maskA[node] = (int)mask; }
    // hn1 = x @ W1 (lane = out dim, broadcast x via shuffle)
    float acc = 0.f;
#pragma unroll
    for (int fp = 0; fp < 64; ++fp) {
        float xA = __shfl(xa, fp);
        float xB = __shfl(xb, fp);
        acc += xA * w1[(2 * fp) * H_ + lane] + xB * w1[(2 * fp + 1) * H_ + lane];
    }
    y1[node * H_ + lane] = acc * is;
}

// ---------------- layer1 aggregate + epilogue + fused h1@W2 -> y2 ----------------
__global__ __launch_bounds__(256) void k_layer1(const float* __restrict__ y1,
                                                const float* __restrict__ inv_s,
                                                const int* __restrict__ maskA,
                                                const int* __restrict__ offs,
                                                const int* __restrict__ csr,
                                                const float* __restrict__ P1,
                                                const void* __restrict__ b1,
                                                const void* __restrict__ W2,
                                                const int* __restrict__ flag,
                                                float* __restrict__ y2) {
    __shared__ float w2[H_ * H_], p1[T_ * H_];
    int bf = *flag;
    int tid = threadIdx.x;
    for (int i = tid; i < H_ * H_; i += 256) w2[i] = ld1(W2, i, bf);
    for (int i = tid; i < T_ * H_; i += 256) p1[i] = P1[i];
    __syncthreads();
    int lane = tid & 63, w = tid >> 6;
    int node = blockIdx.x * 4 + w;
    int mask = maskA[node];
    float is = inv_s[node];
    float acc = y1[node * H_ + lane];             // self-loop term
#pragma unroll
    for (int t = 0; t < T_; ++t)
        if (mask & (1 << t)) acc += p1[t * H_ + lane];
    int beg = offs[node], end = offs[node + 1];
    for (int e = beg; e < end; ++e) {
        int s = csr[e];
        acc += y1[s * H_ + lane];
    }
    float h = acc * is + ld1(b1, lane, bf);
    h = (h >= 0.f) ? h : 0.01f * h;               // leaky relu
    // hn2 = h1 @ W2 fused (broadcast via shuffle)
    float a2 = 0.f;
#pragma unroll
    for (int k = 0; k < H_; ++k) a2 += __shfl(h, k) * w2[k * H_ + lane];
    y2[node * H_ + lane] = a2 * is;
}

// ---------------- layer2 aggregate + epilogue + pooling ----------------
__global__ __launch_bounds__(256) void k_layer2(const float* __restrict__ y2,
                                                const float* __restrict__ inv_s,
                                                const int* __restrict__ maskA,
                                                const int* __restrict__ offs,
                                                const int* __restrict__ csr,
                                                const float* __restrict__ P2,
                                                const void* __restrict__ b2,
                                                const int* __restrict__ flag,
                                                float* __restrict__ graph_sum) {
    __shared__ float p2[T_ * H_];
    int bf = *flag;
    int tid = threadIdx.x;
    for (int i = tid; i < T_ * H_; i += 256) p2[i] = P2[i];
    __syncthreads();
    int lane = tid & 63, w = tid >> 6;
    int base = blockIdx.x * 64 + w * 16;          // 16 nodes per wave, same graph
    float b2f = ld1(b2, lane, bf);
    float pool = 0.f;
    for (int q = 0; q < 16; ++q) {
        int node = base + q;
        int mask = maskA[node];
        float is = inv_s[node];
        float acc = y2[node * H_ + lane];
#pragma unroll
        for (int t = 0; t < T_; ++t)
            if (mask & (1 << t)) acc += p2[t * H_ + lane];
        int beg = offs[node], end = offs[node + 1];
        for (int e = beg; e < end; ++e) acc += y2[csr[e] * H_ + lane];
        pool += acc * is + b2f;
    }
    int b = base >> 10;                           // N_ = 1024
    atomicAdd(&graph_sum[b * H_ + lane], pool);
}

// ---------------- pooled emb -> answering head -> softmax ----------------
__global__ __launch_bounds__(64) void k_final(const float* __restrict__ graph_sum,
                                              const float* __restrict__ tok_sum,
                                              const void* __restrict__ Wa,
                                              const void* __restrict__ ba,
                                              const int* __restrict__ flag,
                                              void* __restrict__ out) {
    int bf = *flag;
    int b = blockIdx.x, l = threadIdx.x;
    float e = (tok_sum[l] + graph_sum[b * H_ + l]) * (1.0f / 1034.0f);
    float p0 = e * ld1(Wa, l * 2 + 0, bf);
    float p1 = e * ld1(Wa, l * 2 + 1, bf);
#pragma unroll
    for (int d = 32; d >= 1; d >>= 1) {
        p0 += __shfl_xor(p0, d);
        p1 += __shfl_xor(p1, d);
    }
    if (l == 0) {
        float l0 = p0 + ld1(ba, 0, bf);
        float l1 = p1 + ld1(ba, 1, bf);
        float m = fmaxf(l0, l1);
        float e0 = expf(l0 - m), e1 = expf(l1 - m);
        float s = e0 + e1;
        float o0 = e0 / s, o1 = e1 / s;
        if (bf) {
            ((__hip_bfloat16*)out)[b * 2 + 0] = __float2bfloat16(o0);
            ((__hip_bfloat16*)out)[b * 2 + 1] = __float2bfloat16(o1);
        } else {
            ((float*)out)[b * 2 + 0] = o0;
            ((float*)out)[b * 2 + 1] = o1;
        }
    }
}

extern "C" void kernel_launch(void* const* d_in, const int* in_sizes, int n_in,
                              void* d_out, int out_size, void* d_ws, size_t ws_size,
                              hipStream_t stream) {
    (void)in_sizes; (void)n_in; (void)out_size; (void)ws_size;
    const void* x      = d_in[0];
    const void* tokens = d_in[1];
    const void* W1     = d_in[2];
    const void* b1     = d_in[3];
    const void* W2     = d_in[4];
    const void* b2     = d_in[5];
    const void* Wa     = d_in[6];
    const void* ba     = d_in[7];
    const int* esrc = (const int*)d_in[8];
    const int* edst = (const int*)d_in[9];

    char* w = (char*)d_ws;
    auto alloc = [&](size_t bytes) { void* p = (void*)w; w += (bytes + 255) & ~(size_t)255; return p; };
    int*   in_deg    = (int*)alloc(BN * 4);
    int*   offs      = (int*)alloc((BN + 1) * 4);
    int*   cursor    = (int*)alloc(BN * 4);
    int*   csr       = (int*)alloc(BE * 4);
    int*   maskA     = (int*)alloc(BN * 4);
    float* inv_s     = (float*)alloc(BN * 4);
    float* y1        = (float*)alloc((size_t)BN * H_ * 4);
    float* y2        = (float*)alloc((size_t)BN * H_ * 4);
    float* P1        = (float*)alloc(T_ * H_ * 4);
    float* P2        = (float*)alloc(T_ * H_ * 4);
    float* tok_sum   = (float*)alloc(H_ * 4);
    float* graph_sum = (float*)alloc(B_ * H_ * 4);
    int*   dflag     = (int*)alloc(256);

    hipMemsetAsync(in_deg, 0, BN * 4, stream);
    hipMemsetAsync(graph_sum, 0, B_ * H_ * 4, stream);

    k_detect<<<1, 64, 0, stream>>>(tokens, dflag);
    k_deg   <<<BE / 256, 256, 0, stream>>>(edst, in_deg);
    k_tok   <<<1, 64, 0, stream>>>(tokens, W1, b1, W2, b2, dflag, P1, P2, tok_sum);
    k_scan  <<<1, 1024, 0, stream>>>(in_deg, offs, cursor);
    k_fill  <<<BE / 256, 256, 0, stream>>>(esrc, edst, cursor, csr);
    k_node1 <<<BN / 4, 256, 0, stream>>>(x, tokens, W1, in_deg, dflag, y1, inv_s, maskA);
    k_layer1<<<BN / 4, 256, 0, stream>>>(y1, inv_s, maskA, offs, csr, P1, b1, W2, dflag, y2);
    k_layer2<<<BN / 64, 256, 0, stream>>>(y2, inv_s, maskA, offs, csr, P2, b2, dflag, graph_sum);
    k_final <<<B_, 64, 0, stream>>>(graph_sum, tok_sum, Wa, ba, dflag, d_out);
}

// Round 3
// 440.968 us; speedup vs baseline: 1.7237x; 1.7237x over previous
//
#include <hip/hip_runtime.h>
#include <hip/hip_bf16.h>
#include <stdint.h>

#define B_ 64
#define N_ 1024
#define E_ 16384
#define F_ 128
#define H_ 64
#define T_ 10
#define BN (B_*N_)   // 65536
#define BE (B_*E_)   // 1048576

// sigmoid(z) >= p  <=>  z >= log(p/(1-p))
#define TH_INNER (-0.84729786f)   // logit(0.3)
#define TH_CROSS (-2.1972246f)    // logit(0.1)

typedef __attribute__((ext_vector_type(8))) short short8;  // bf16x8 MFMA frag
typedef __attribute__((ext_vector_type(4))) float f32x4;   // MFMA acc

// ---- dtype-agnostic loads: bf=1 -> packed bf16, bf=0 -> float32 ----
__device__ __forceinline__ float ld1(const void* p, int i, int bf) {
    if (bf) {
        uint16_t u = ((const uint16_t*)p)[i];
        return __uint_as_float(((uint32_t)u) << 16);
    }
    return ((const float*)p)[i];
}

__device__ __forceinline__ short to_bf(float x) {
    return (short)__bfloat16_as_ushort(__float2bfloat16(x));
}

// ---------------- dtype detection (1 wave) ----------------
__global__ __launch_bounds__(64) void k_detect(const void* __restrict__ tokens,
                                               int* __restrict__ flag) {
    int l = threadIdx.x;
    uint32_t u = ((const uint32_t*)tokens)[l];
    float lo = __uint_as_float(u << 16);
    int ok = (fabsf(lo) <= 1.0f) ? 1 : 0;   // NaN -> 0
    unsigned long long vote = __ballot(ok);
    if (l == 0) *flag = (vote == ~0ull) ? 1 : 0;
}

// ---------------- in-degree via atomics ----------------
__global__ __launch_bounds__(256) void k_deg(const int* __restrict__ dst,
                                             int* __restrict__ in_deg) {
    int i = blockIdx.x * 256 + threadIdx.x;
    int b = i >> 14;                             // E_ = 2^14
    atomicAdd(&in_deg[b * N_ + dst[i]], 1);
}

// ---------------- exclusive scan (single block) ----------------
__global__ __launch_bounds__(1024) void k_scan(const int* __restrict__ in_deg,
                                               int* __restrict__ offs,
                                               int* __restrict__ cursor) {
    __shared__ int sums[1024];
    int t = threadIdx.x;
    int base = t * 64;
    int s = 0;
    for (int i = 0; i < 64; ++i) s += in_deg[base + i];
    sums[t] = s;
    __syncthreads();
    for (int d = 1; d < 1024; d <<= 1) {
        int v = (t >= d) ? sums[t - d] : 0;
        __syncthreads();
        sums[t] += v;
        __syncthreads();
    }
    int start = (t == 0) ? 0 : sums[t - 1];
    for (int i = 0; i < 64; ++i) {
        int v = in_deg[base + i];
        offs[base + i] = start;
        cursor[base + i] = start;
        start += v;
    }
    if (t == 1023) offs[BN] = start;
}

// ---------------- CSR fill ----------------
__global__ __launch_bounds__(256) void k_fill(const int* __restrict__ src,
                                              const int* __restrict__ dst,
                                              int* __restrict__ cursor,
                                              int* __restrict__ csr) {
    int i = blockIdx.x * 256 + threadIdx.x;
    int b = i >> 14;
    int d = b * N_ + dst[i];
    int p = atomicAdd(&cursor[d], 1);
    csr[p] = b * N_ + src[i];
}

// ---------------- build swizzled B fragments for node GEMM ----------------
// Bcat[k][n]: n<64 -> W1[k][n]; 64<=n<74 -> tokens[n-64][k]; else 0. [128 x 80]
// Frag (c,nt,lane): k0 = c*32 + (lane>>4)*8, n = nt*16 + (lane&15), j=0..7.
__global__ __launch_bounds__(256) void k_prep(const void* __restrict__ W1,
                                              const void* __restrict__ tokens,
                                              const int* __restrict__ flag,
                                              short8* __restrict__ Bfr) {
    int bf = *flag;
    int f = blockIdx.x * 256 + threadIdx.x;      // [0, 1280)
    int c = f / 320, rem = f % 320;
    int nt = rem / 64, lane = rem % 64;
    int q = lane >> 4, n = nt * 16 + (lane & 15);
    int k0 = c * 32 + q * 8;
    short8 v;
#pragma unroll
    for (int j = 0; j < 8; ++j) {
        int k = k0 + j;
        float x = 0.f;
        if (n < H_) x = ld1(W1, k * H_ + n, bf);
        else if (n < H_ + T_) x = ld1(tokens, (n - H_) * F_ + k, bf);
        v[j] = to_bf(x);
    }
    Bfr[f] = v;
}

// ---------------- token stream (graph-independent), one block of 64 ----------------
__global__ __launch_bounds__(64) void k_tok(const void* __restrict__ tokens,
                                            const void* __restrict__ W1,
                                            const void* __restrict__ b1,
                                            const void* __restrict__ W2,
                                            const void* __restrict__ b2,
                                            const int* __restrict__ flag,
                                            float* __restrict__ P1,
                                            float* __restrict__ P2,
                                            float* __restrict__ tok_sum) {
    __shared__ float tk[T_ * F_], w1[F_ * H_], w2[H_ * H_];
    __shared__ float Min[T_ * T_], ist[T_], idt[T_], h1s[T_ * H_];
    int bf = *flag;
    int l = threadIdx.x;
    for (int i = l; i < T_ * F_; i += 64) tk[i] = ld1(tokens, i, bf);
    for (int i = l; i < F_ * H_; i += 64) w1[i] = ld1(W1, i, bf);
    for (int i = l; i < H_ * H_; i += 64) w2[i] = ld1(W2, i, bf);
    __syncthreads();
    for (int p = l; p < T_ * T_; p += 64) {
        int i = p / T_, j = p % T_;
        float s = 0.f;
        for (int f = 0; f < F_; ++f) s += tk[i * F_ + f] * tk[j * F_ + f];
        Min[p] = (s >= TH_INNER) ? 1.f : 0.f;
    }
    __syncthreads();
    if (l < T_) {
        float d = 1.f;
        for (int s = 0; s < T_; ++s) d += Min[s * T_ + l];
        ist[l] = 1.f / sqrtf(d);
        idt[l] = 1.f / d;
    }
    __syncthreads();
    float ht1[T_];
    for (int t = 0; t < T_; ++t) {
        float a = 0.f;
        for (int f = 0; f < F_; ++f) a += tk[t * F_ + f] * w1[f * H_ + l];
        ht1[t] = a;
    }
    float b1f = ld1(b1, l, bf);
    for (int t = 0; t < T_; ++t) {
        float a = ht1[t] * idt[t] + b1f;
        for (int s = 0; s < T_; ++s) a += Min[t * T_ + s] * ist[t] * ist[s] * ht1[s];
        a = (a >= 0.f) ? a : 0.01f * a;
        h1s[t * H_ + l] = a;
        P1[t * H_ + l] = ist[t] * ht1[t];
    }
    __syncthreads();
    float ht2[T_];
    for (int t = 0; t < T_; ++t) {
        float a = 0.f;
        for (int k = 0; k < H_; ++k) a += h1s[t * H_ + k] * w2[k * H_ + l];
        ht2[t] = a;
        P2[t * H_ + l] = ist[t] * a;
    }
    float b2f = ld1(b2, l, bf);
    float ts = 0.f;
    for (int t = 0; t < T_; ++t) {
        float o = ht2[t] * idt[t] + b2f;
        for (int s = 0; s < T_; ++s) o += Min[t * T_ + s] * ist[t] * ist[s] * ht2[s];
        ts += o;
    }
    tok_sum[l] = ts;
}

// ---------------- node GEMM via MFMA: y1 + cross masks + inv_s ----------------
// OUT[BN x 80] = X[BN x 128] @ Bcat[128 x 80]; cols 0..63 = x@W1, 64..73 = z_t.
__global__ __launch_bounds__(256) void k_node_mfma(const void* __restrict__ x,
                                                   const short8* __restrict__ Bfr,
                                                   const int* __restrict__ in_deg,
                                                   const int* __restrict__ flag,
                                                   float* __restrict__ y1,
                                                   float* __restrict__ inv_s,
                                                   int* __restrict__ maskA) {
    int bf = *flag;
    int tid = threadIdx.x;
    int lane = tid & 63, wv = tid >> 6;
    int row0 = blockIdx.x * 64 + wv * 16;        // 16-row strip per wave
    int m = lane & 15, q = lane >> 4;
    int row = row0 + m;
    short8 afr[4];
    if (bf) {
        const short8* ar = (const short8*)((const uint16_t*)x + (size_t)row * F_);
#pragma unroll
        for (int c = 0; c < 4; ++c) afr[c] = ar[c * 4 + q];
    } else {
        const float* ar = (const float*)x + (size_t)row * F_;
#pragma unroll
        for (int c = 0; c < 4; ++c)
#pragma unroll
            for (int j = 0; j < 8; ++j)
                afr[c][j] = to_bf(ar[c * 32 + q * 8 + j]);
    }
    f32x4 acc[5] = {};
#pragma unroll
    for (int nt = 0; nt < 5; ++nt)
#pragma unroll
        for (int c = 0; c < 4; ++c) {
            short8 bfr = Bfr[(c * 5 + nt) * 64 + lane];
            acc[nt] = __builtin_amdgcn_mfma_f32_16x16x32_bf16(afr[c], bfr, acc[nt], 0, 0, 0);
        }
    // cross-prune masks from z tile (acc[4], in-tile cols 0..9 = tokens)
    unsigned long long bal[4];
#pragma unroll
    for (int r = 0; r < 4; ++r) {
        int pred = (m < T_) && (acc[4][r] >= TH_CROSS);
        bal[r] = __ballot(pred);
    }
    float isv[4]; int msk[4];
#pragma unroll
    for (int r = 0; r < 4; ++r) {
        int node = row0 + q * 4 + r;
        int mask = (int)((bal[r] >> (q * 16)) & 0x3FF);
        float deg = 1.f + (float)in_deg[node] + (float)__popc((unsigned)mask);
        isv[r] = 1.f / sqrtf(deg);
        msk[r] = mask;
    }
    if (m == 0) {
#pragma unroll
        for (int r = 0; r < 4; ++r) {
            inv_s[row0 + q * 4 + r] = isv[r];
            maskA[row0 + q * 4 + r] = msk[r];
        }
    }
#pragma unroll
    for (int nt = 0; nt < 4; ++nt)
#pragma unroll
        for (int r = 0; r < 4; ++r)
            y1[(size_t)(row0 + q * 4 + r) * H_ + nt * 16 + m] = acc[nt][r] * isv[r];
}

// ---------------- batched CSR gather: sum rows of ybuf over csr[beg:end) ----------------
__device__ __forceinline__ float gather64(const float* __restrict__ ybuf,
                                          const int* __restrict__ csr,
                                          int beg, int end, int lane) {
    float acc = 0.f;
    for (int eb = beg; eb < end; eb += 64) {
        int idx = (eb + lane < end) ? csr[eb + lane] : 0;
        int cnt = min(64, end - eb);
        int e = 0;
        for (; e + 4 <= cnt; e += 4) {
            int s0 = __shfl(idx, e), s1 = __shfl(idx, e + 1);
            int s2 = __shfl(idx, e + 2), s3 = __shfl(idx, e + 3);
            float v0 = ybuf[(size_t)s0 * H_ + lane];
            float v1 = ybuf[(size_t)s1 * H_ + lane];
            float v2 = ybuf[(size_t)s2 * H_ + lane];
            float v3 = ybuf[(size_t)s3 * H_ + lane];
            acc += v0 + v1 + v2 + v3;
        }
        for (; e < cnt; ++e) {
            int s = __shfl(idx, e);
            acc += ybuf[(size_t)s * H_ + lane];
        }
    }
    return acc;
}

// ---------------- layer1 aggregate + epilogue + fused h1@W2 -> y2 ----------------
__global__ __launch_bounds__(256) void k_layer1(const float* __restrict__ y1,
                                                const float* __restrict__ inv_s,
                                                const int* __restrict__ maskA,
                                                const int* __restrict__ offs,
                                                const int* __restrict__ csr,
                                                const float* __restrict__ P1,
                                                const void* __restrict__ b1,
                                                const void* __restrict__ W2,
                                                const int* __restrict__ flag,
                                                float* __restrict__ y2) {
    __shared__ float w2[H_ * H_], p1[T_ * H_];
    int bf = *flag;
    int tid = threadIdx.x;
    for (int i = tid; i < H_ * H_; i += 256) w2[i] = ld1(W2, i, bf);
    for (int i = tid; i < T_ * H_; i += 256) p1[i] = P1[i];
    __syncthreads();
    int lane = tid & 63, wv = tid >> 6;
    float b1f = ld1(b1, lane, bf);
    for (int qq = 0; qq < 4; ++qq) {
        int node = blockIdx.x * 16 + wv * 4 + qq;
        int mask = maskA[node];
        float is = inv_s[node];
        float acc = y1[(size_t)node * H_ + lane];   // self-loop term
#pragma unroll
        for (int t = 0; t < T_; ++t)
            if (mask & (1 << t)) acc += p1[t * H_ + lane];
        acc += gather64(y1, csr, offs[node], offs[node + 1], lane);
        float h = acc * is + b1f;
        h = (h >= 0.f) ? h : 0.01f * h;             // leaky relu
        float a2 = 0.f;
#pragma unroll
        for (int k = 0; k < H_; ++k) a2 += __shfl(h, k) * w2[k * H_ + lane];
        y2[(size_t)node * H_ + lane] = a2 * is;
    }
}

// ---------------- layer2 aggregate + epilogue + pooling ----------------
__global__ __launch_bounds__(256) void k_layer2(const float* __restrict__ y2,
                                                const float* __restrict__ inv_s,
                                                const int* __restrict__ maskA,
                                                const int* __restrict__ offs,
                                                const int* __restrict__ csr,
                                                const float* __restrict__ P2,
                                                const void* __restrict__ b2,
                                                const int* __restrict__ flag,
                                                float* __restrict__ graph_sum) {
    __shared__ float p2[T_ * H_];
    int bf = *flag;
    int tid = threadIdx.x;
    for (int i = tid; i < T_ * H_; i += 256) p2[i] = P2[i];
    __syncthreads();
    int lane = tid & 63, wv = tid >> 6;
    int base = blockIdx.x * 64 + wv * 16;           // 16 nodes per wave, same graph
    float b2f = ld1(b2, lane, bf);
    float pool = 0.f;
    for (int qv = 0; qv < 16; ++qv) {
        int node = base + qv;
        int mask = maskA[node];
        float is = inv_s[node];
        float acc = y2[(size_t)node * H_ + lane];
#pragma unroll
        for (int t = 0; t < T_; ++t)
            if (mask & (1 << t)) acc += p2[t * H_ + lane];
        acc += gather64(y2, csr, offs[node], offs[node + 1], lane);
        pool += acc * is + b2f;
    }
    int b = base >> 10;                             // N_ = 1024
    atomicAdd(&graph_sum[b * H_ + lane], pool);
}

// ---------------- pooled emb -> answering head -> softmax ----------------
__global__ __launch_bounds__(64) void k_final(const float* __restrict__ graph_sum,
                                              const float* __restrict__ tok_sum,
                                              const void* __restrict__ Wa,
                                              const void* __restrict__ ba,
                                              const int* __restrict__ flag,
                                              void* __restrict__ out) {
    int bf = *flag;
    int b = blockIdx.x, l = threadIdx.x;
    float e = (tok_sum[l] + graph_sum[b * H_ + l]) * (1.0f / 1034.0f);
    float p0 = e * ld1(Wa, l * 2 + 0, bf);
    float p1 = e * ld1(Wa, l * 2 + 1, bf);
#pragma unroll
    for (int d = 32; d >= 1; d >>= 1) {
        p0 += __shfl_xor(p0, d);
        p1 += __shfl_xor(p1, d);
    }
    if (l == 0) {
        float l0 = p0 + ld1(ba, 0, bf);
        float l1 = p1 + ld1(ba, 1, bf);
        float mx = fmaxf(l0, l1);
        float e0 = expf(l0 - mx), e1 = expf(l1 - mx);
        float s = e0 + e1;
        float o0 = e0 / s, o1 = e1 / s;
        if (bf) {
            ((__hip_bfloat16*)out)[b * 2 + 0] = __float2bfloat16(o0);
            ((__hip_bfloat16*)out)[b * 2 + 1] = __float2bfloat16(o1);
        } else {
            ((float*)out)[b * 2 + 0] = o0;
            ((float*)out)[b * 2 + 1] = o1;
        }
    }
}

extern "C" void kernel_launch(void* const* d_in, const int* in_sizes, int n_in,
                              void* d_out, int out_size, void* d_ws, size_t ws_size,
                              hipStream_t stream) {
    (void)in_sizes; (void)n_in; (void)out_size; (void)ws_size;
    const void* x      = d_in[0];
    const void* tokens = d_in[1];
    const void* W1     = d_in[2];
    const void* b1     = d_in[3];
    const void* W2     = d_in[4];
    const void* b2     = d_in[5];
    const void* Wa     = d_in[6];
    const void* ba     = d_in[7];
    const int* esrc = (const int*)d_in[8];
    const int* edst = (const int*)d_in[9];

    char* w = (char*)d_ws;
    auto alloc = [&](size_t bytes) { void* p = (void*)w; w += (bytes + 255) & ~(size_t)255; return p; };
    int*    in_deg    = (int*)alloc(BN * 4);
    int*    offs      = (int*)alloc((BN + 1) * 4);
    int*    cursor    = (int*)alloc(BN * 4);
    int*    csr       = (int*)alloc(BE * 4);
    int*    maskA     = (int*)alloc(BN * 4);
    float*  inv_s     = (float*)alloc(BN * 4);
    float*  y1        = (float*)alloc((size_t)BN * H_ * 4);
    float*  y2        = (float*)alloc((size_t)BN * H_ * 4);
    float*  P1        = (float*)alloc(T_ * H_ * 4);
    float*  P2        = (float*)alloc(T_ * H_ * 4);
    float*  tok_sum   = (float*)alloc(H_ * 4);
    float*  graph_sum = (float*)alloc(B_ * H_ * 4);
    short8* Bfr       = (short8*)alloc(4 * 5 * 64 * sizeof(short8));
    int*    dflag     = (int*)alloc(256);

    hipMemsetAsync(in_deg, 0, BN * 4, stream);
    hipMemsetAsync(graph_sum, 0, B_ * H_ * 4, stream);

    k_detect   <<<1, 64, 0, stream>>>(tokens, dflag);
    k_deg      <<<BE / 256, 256, 0, stream>>>(edst, in_deg);
    k_prep     <<<5, 256, 0, stream>>>(W1, tokens, dflag, Bfr);
    k_tok      <<<1, 64, 0, stream>>>(tokens, W1, b1, W2, b2, dflag, P1, P2, tok_sum);
    k_scan     <<<1, 1024, 0, stream>>>(in_deg, offs, cursor);
    k_fill     <<<BE / 256, 256, 0, stream>>>(esrc, edst, cursor, csr);
    k_node_mfma<<<BN / 64, 256, 0, stream>>>(x, Bfr, in_deg, dflag, y1, inv_s, maskA);
    k_layer1   <<<BN / 16, 256, 0, stream>>>(y1, inv_s, maskA, offs, csr, P1, b1, W2, dflag, y2);
    k_layer2   <<<BN / 64, 256, 0, stream>>>(y2, inv_s, maskA, offs, csr, P2, b2, dflag, graph_sum);
    k_final    <<<B_, 64, 0, stream>>>(graph_sum, tok_sum, Wa, ba, dflag, d_out);
}

// Round 4
// 417.420 us; speedup vs baseline: 1.8209x; 1.0564x over previous
//
#include <hip/hip_runtime.h>
#include <hip/hip_bf16.h>
#include <stdint.h>

#define B_ 64
#define N_ 1024
#define E_ 16384
#define F_ 128
#define H_ 64
#define T_ 10
#define BN (B_*N_)   // 65536
#define BE (B_*E_)   // 1048576

// sigmoid(z) >= p  <=>  z >= log(p/(1-p))
#define TH_INNER (-0.84729786f)   // logit(0.3)
#define TH_CROSS (-2.1972246f)    // logit(0.1)

typedef __attribute__((ext_vector_type(8))) short short8;  // bf16x8 MFMA frag
typedef __attribute__((ext_vector_type(4))) float f32x4;   // MFMA acc

// ---- dtype-agnostic loads: bf=1 -> packed bf16, bf=0 -> float32 ----
__device__ __forceinline__ float ld1(const void* p, int i, int bf) {
    if (bf) {
        uint16_t u = ((const uint16_t*)p)[i];
        return __uint_as_float(((uint32_t)u) << 16);
    }
    return ((const float*)p)[i];
}

__device__ __forceinline__ short to_bf(float x) {
    return (short)__bfloat16_as_ushort(__float2bfloat16(x));
}

__device__ __forceinline__ uint32_t pack_bf2(float lo, float hi) {
    uint32_t l = (uint32_t)__bfloat16_as_ushort(__float2bfloat16(lo));
    uint32_t h = (uint32_t)__bfloat16_as_ushort(__float2bfloat16(hi));
    return l | (h << 16);
}

// ---------------- dtype detection (1 wave) ----------------
__global__ __launch_bounds__(64) void k_detect(const void* __restrict__ tokens,
                                               int* __restrict__ flag) {
    int l = threadIdx.x;
    uint32_t u = ((const uint32_t*)tokens)[l];
    float lo = __uint_as_float(u << 16);
    int ok = (fabsf(lo) <= 1.0f) ? 1 : 0;   // NaN -> 0
    unsigned long long vote = __ballot(ok);
    if (l == 0) *flag = (vote == ~0ull) ? 1 : 0;
}

// ---------------- in-degree via atomics ----------------
__global__ __launch_bounds__(256) void k_deg(const int* __restrict__ dst,
                                             int* __restrict__ in_deg) {
    int i = blockIdx.x * 256 + threadIdx.x;
    int b = i >> 14;                             // E_ = 2^14
    atomicAdd(&in_deg[b * N_ + dst[i]], 1);
}

// ---------------- exclusive scan (single block) ----------------
__global__ __launch_bounds__(1024) void k_scan(const int* __restrict__ in_deg,
                                               int* __restrict__ offs,
                                               int* __restrict__ cursor) {
    __shared__ int sums[1024];
    int t = threadIdx.x;
    int base = t * 64;
    int s = 0;
    for (int i = 0; i < 64; ++i) s += in_deg[base + i];
    sums[t] = s;
    __syncthreads();
    for (int d = 1; d < 1024; d <<= 1) {
        int v = (t >= d) ? sums[t - d] : 0;
        __syncthreads();
        sums[t] += v;
        __syncthreads();
    }
    int start = (t == 0) ? 0 : sums[t - 1];
    for (int i = 0; i < 64; ++i) {
        int v = in_deg[base + i];
        offs[base + i] = start;
        cursor[base + i] = start;
        start += v;
    }
    if (t == 1023) offs[BN] = start;
}

// ---------------- CSR fill ----------------
__global__ __launch_bounds__(256) void k_fill(const int* __restrict__ src,
                                              const int* __restrict__ dst,
                                              int* __restrict__ cursor,
                                              int* __restrict__ csr) {
    int i = blockIdx.x * 256 + threadIdx.x;
    int b = i >> 14;
    int d = b * N_ + dst[i];
    int p = atomicAdd(&cursor[d], 1);
    csr[p] = b * N_ + src[i];
}

// ---------------- build swizzled B fragments for node GEMM ----------------
__global__ __launch_bounds__(256) void k_prep(const void* __restrict__ W1,
                                              const void* __restrict__ tokens,
                                              const int* __restrict__ flag,
                                              short8* __restrict__ Bfr) {
    int bf = *flag;
    int f = blockIdx.x * 256 + threadIdx.x;      // [0, 1280)
    int c = f / 320, rem = f % 320;
    int nt = rem / 64, lane = rem % 64;
    int q = lane >> 4, n = nt * 16 + (lane & 15);
    int k0 = c * 32 + q * 8;
    short8 v;
#pragma unroll
    for (int j = 0; j < 8; ++j) {
        int k = k0 + j;
        float x = 0.f;
        if (n < H_) x = ld1(W1, k * H_ + n, bf);
        else if (n < H_ + T_) x = ld1(tokens, (n - H_) * F_ + k, bf);
        v[j] = to_bf(x);
    }
    Bfr[f] = v;
}

// ---------------- token stream (graph-independent), one block of 64 ----------------
__global__ __launch_bounds__(64) void k_tok(const void* __restrict__ tokens,
                                            const void* __restrict__ W1,
                                            const void* __restrict__ b1,
                                            const void* __restrict__ W2,
                                            const void* __restrict__ b2,
                                            const int* __restrict__ flag,
                                            float* __restrict__ P1,
                                            float* __restrict__ P2,
                                            float* __restrict__ tok_sum) {
    __shared__ float tk[T_ * F_], w1[F_ * H_], w2[H_ * H_];
    __shared__ float Min[T_ * T_], ist[T_], idt[T_], h1s[T_ * H_];
    int bf = *flag;
    int l = threadIdx.x;
    for (int i = l; i < T_ * F_; i += 64) tk[i] = ld1(tokens, i, bf);
    for (int i = l; i < F_ * H_; i += 64) w1[i] = ld1(W1, i, bf);
    for (int i = l; i < H_ * H_; i += 64) w2[i] = ld1(W2, i, bf);
    __syncthreads();
    for (int p = l; p < T_ * T_; p += 64) {
        int i = p / T_, j = p % T_;
        float s = 0.f;
        for (int f = 0; f < F_; ++f) s += tk[i * F_ + f] * tk[j * F_ + f];
        Min[p] = (s >= TH_INNER) ? 1.f : 0.f;
    }
    __syncthreads();
    if (l < T_) {
        float d = 1.f;
        for (int s = 0; s < T_; ++s) d += Min[s * T_ + l];
        ist[l] = 1.f / sqrtf(d);
        idt[l] = 1.f / d;
    }
    __syncthreads();
    float ht1[T_];
    for (int t = 0; t < T_; ++t) {
        float a = 0.f;
        for (int f = 0; f < F_; ++f) a += tk[t * F_ + f] * w1[f * H_ + l];
        ht1[t] = a;
    }
    float b1f = ld1(b1, l, bf);
    for (int t = 0; t < T_; ++t) {
        float a = ht1[t] * idt[t] + b1f;
        for (int s = 0; s < T_; ++s) a += Min[t * T_ + s] * ist[t] * ist[s] * ht1[s];
        a = (a >= 0.f) ? a : 0.01f * a;
        h1s[t * H_ + l] = a;
        P1[t * H_ + l] = ist[t] * ht1[t];
    }
    __syncthreads();
    float ht2[T_];
    for (int t = 0; t < T_; ++t) {
        float a = 0.f;
        for (int k = 0; k < H_; ++k) a += h1s[t * H_ + k] * w2[k * H_ + l];
        ht2[t] = a;
        P2[t * H_ + l] = ist[t] * a;
    }
    float b2f = ld1(b2, l, bf);
    float ts = 0.f;
    for (int t = 0; t < T_; ++t) {
        float o = ht2[t] * idt[t] + b2f;
        for (int s = 0; s < T_; ++s) o += Min[t * T_ + s] * ist[t] * ist[s] * ht2[s];
        ts += o;
    }
    tok_sum[l] = ts;
}

// ---------------- node GEMM via MFMA: y1(bf16 packed) + cross masks + inv_s ----------------
__global__ __launch_bounds__(256) void k_node_mfma(const void* __restrict__ x,
                                                   const short8* __restrict__ Bfr,
                                                   const int* __restrict__ in_deg,
                                                   const int* __restrict__ flag,
                                                   uint32_t* __restrict__ y1,
                                                   float* __restrict__ inv_s,
                                                   int* __restrict__ maskA) {
    int bf = *flag;
    int tid = threadIdx.x;
    int lane = tid & 63, wv = tid >> 6;
    int row0 = blockIdx.x * 64 + wv * 16;        // 16-row strip per wave
    int m = lane & 15, q = lane >> 4;
    int row = row0 + m;
    short8 afr[4];
    if (bf) {
        const short8* ar = (const short8*)((const uint16_t*)x + (size_t)row * F_);
#pragma unroll
        for (int c = 0; c < 4; ++c) afr[c] = ar[c * 4 + q];
    } else {
        const float* ar = (const float*)x + (size_t)row * F_;
#pragma unroll
        for (int c = 0; c < 4; ++c)
#pragma unroll
            for (int j = 0; j < 8; ++j)
                afr[c][j] = to_bf(ar[c * 32 + q * 8 + j]);
    }
    f32x4 acc[5] = {};
#pragma unroll
    for (int nt = 0; nt < 5; ++nt)
#pragma unroll
        for (int c = 0; c < 4; ++c) {
            short8 bfr = Bfr[(c * 5 + nt) * 64 + lane];
            acc[nt] = __builtin_amdgcn_mfma_f32_16x16x32_bf16(afr[c], bfr, acc[nt], 0, 0, 0);
        }
    unsigned long long bal[4];
#pragma unroll
    for (int r = 0; r < 4; ++r) {
        int pred = (m < T_) && (acc[4][r] >= TH_CROSS);
        bal[r] = __ballot(pred);
    }
    float isv[4];
#pragma unroll
    for (int r = 0; r < 4; ++r) {
        int node = row0 + q * 4 + r;
        int mask = (int)((bal[r] >> (q * 16)) & 0x3FF);
        float deg = 1.f + (float)in_deg[node] + (float)__popc((unsigned)mask);
        isv[r] = 1.f / sqrtf(deg);
        if (m == 0) { inv_s[node] = isv[r]; maskA[node] = mask; }
    }
    // packed bf16 pair writes: features nt*16+m (even m takes own + lane+1)
#pragma unroll
    for (int r = 0; r < 4; ++r) {
        int node = row0 + q * 4 + r;
#pragma unroll
        for (int nt = 0; nt < 4; ++nt) {
            float v = acc[nt][r] * isv[r];
            float vh = __shfl(v, lane + 1);
            if ((m & 1) == 0)
                y1[(size_t)node * 32 + nt * 8 + (m >> 1)] = pack_bf2(v, vh);
        }
    }
}

// ---------------- pair-domain CSR gather over packed-bf16 rows ----------------
// lane = (half h = lane>>5) * 32 + feature-pair fp; 2 rows per wave-load.
// Returns feature-domain value for feature `lane` via remap.
__device__ __forceinline__ float gather_bf(const uint32_t* __restrict__ yu,
                                           const int* __restrict__ csr,
                                           int beg, int end, int lane) {
    int h = lane >> 5, fp = lane & 31;
    float aLo = 0.f, aHi = 0.f;
    for (int eb = beg; eb < end; eb += 64) {
        int idx = (eb + lane < end) ? csr[eb + lane] : BN;   // BN = zero row
        int cnt = min(64, end - eb);
        int np = (cnt + 1) >> 1;
        int p = 0;
        for (; p + 4 <= np; p += 4) {
            int s0 = __shfl(idx, 2 * (p + 0) + h);
            int s1 = __shfl(idx, 2 * (p + 1) + h);
            int s2 = __shfl(idx, 2 * (p + 2) + h);
            int s3 = __shfl(idx, 2 * (p + 3) + h);
            uint32_t u0 = yu[(size_t)s0 * 32 + fp];
            uint32_t u1 = yu[(size_t)s1 * 32 + fp];
            uint32_t u2 = yu[(size_t)s2 * 32 + fp];
            uint32_t u3 = yu[(size_t)s3 * 32 + fp];
            aLo += __uint_as_float(u0 << 16) + __uint_as_float(u1 << 16)
                 + __uint_as_float(u2 << 16) + __uint_as_float(u3 << 16);
            aHi += __uint_as_float(u0 & 0xffff0000u) + __uint_as_float(u1 & 0xffff0000u)
                 + __uint_as_float(u2 & 0xffff0000u) + __uint_as_float(u3 & 0xffff0000u);
        }
        for (; p < np; ++p) {
            int s = __shfl(idx, 2 * p + h);
            uint32_t u = yu[(size_t)s * 32 + fp];
            aLo += __uint_as_float(u << 16);
            aHi += __uint_as_float(u & 0xffff0000u);
        }
    }
    // combine halves (each processed disjoint edges of the same node)
    aLo += __shfl_xor(aLo, 32);
    aHi += __shfl_xor(aHi, 32);
    // remap pair-domain -> feature-domain (feature = lane)
    float a = __shfl(aLo, lane >> 1);
    float b = __shfl(aHi, lane >> 1);
    return (lane & 1) ? b : a;
}

// ---------------- layer1 aggregate + epilogue + fused h1@W2 -> y2 (bf16) ----------------
__global__ __launch_bounds__(256) void k_layer1(const uint32_t* __restrict__ y1,
                                                const float* __restrict__ inv_s,
                                                const int* __restrict__ maskA,
                                                const int* __restrict__ offs,
                                                const int* __restrict__ csr,
                                                const float* __restrict__ P1,
                                                const void* __restrict__ b1,
                                                const void* __restrict__ W2,
                                                const int* __restrict__ flag,
                                                uint32_t* __restrict__ y2) {
    __shared__ float w2[H_ * H_], p1[T_ * H_];
    int bf = *flag;
    int tid = threadIdx.x;
    for (int i = tid; i < H_ * H_; i += 256) w2[i] = ld1(W2, i, bf);
    for (int i = tid; i < T_ * H_; i += 256) p1[i] = P1[i];
    __syncthreads();
    int lane = tid & 63, wv = tid >> 6;
    // XCD swizzle: graph g = blockIdx%64 -> XCD g%8; chunk c = blockIdx/64
    int g = blockIdx.x & 63, c = blockIdx.x >> 6;
    float b1f = ld1(b1, lane, bf);
    for (int qq = 0; qq < 4; ++qq) {
        int node = g * N_ + c * 16 + wv * 4 + qq;
        int mask = maskA[node];
        float is = inv_s[node];
        float acc = gather_bf(y1, csr, offs[node], offs[node + 1], lane);
        // self-loop (feature domain, bf16 scalar)
        uint16_t su = ((const uint16_t*)y1)[(size_t)node * 64 + lane];
        acc += __uint_as_float(((uint32_t)su) << 16);
#pragma unroll
        for (int t = 0; t < T_; ++t)
            if (mask & (1 << t)) acc += p1[t * H_ + lane];
        float h = acc * is + b1f;
        h = (h >= 0.f) ? h : 0.01f * h;             // leaky relu
        float a2 = 0.f;
#pragma unroll
        for (int k = 0; k < H_; ++k) a2 += __shfl(h, k) * w2[k * H_ + lane];
        float v = a2 * is;
        float vh = __shfl(v, lane + 1);
        if ((lane & 1) == 0)
            y2[(size_t)node * 32 + (lane >> 1)] = pack_bf2(v, vh);
    }
}

// ---------------- layer2 aggregate + epilogue + pooling ----------------
__global__ __launch_bounds__(256) void k_layer2(const uint32_t* __restrict__ y2,
                                                const float* __restrict__ inv_s,
                                                const int* __restrict__ maskA,
                                                const int* __restrict__ offs,
                                                const int* __restrict__ csr,
                                                const float* __restrict__ P2,
                                                const void* __restrict__ b2,
                                                const int* __restrict__ flag,
                                                float* __restrict__ graph_sum) {
    __shared__ float p2[T_ * H_];
    int bf = *flag;
    int tid = threadIdx.x;
    for (int i = tid; i < T_ * H_; i += 256) p2[i] = P2[i];
    __syncthreads();
    int lane = tid & 63, wv = tid >> 6;
    int g = blockIdx.x & 63, c = blockIdx.x >> 6;   // 1024 blocks: c in [0,16)
    int base = g * N_ + c * 64 + wv * 16;
    float b2f = ld1(b2, lane, bf);
    float pool = 0.f;
    for (int qv = 0; qv < 16; ++qv) {
        int node = base + qv;
        int mask = maskA[node];
        float is = inv_s[node];
        float acc = gather_bf(y2, csr, offs[node], offs[node + 1], lane);
        uint16_t su = ((const uint16_t*)y2)[(size_t)node * 64 + lane];
        acc += __uint_as_float(((uint32_t)su) << 16);
#pragma unroll
        for (int t = 0; t < T_; ++t)
            if (mask & (1 << t)) acc += p2[t * H_ + lane];
        pool += acc * is + b2f;
    }
    atomicAdd(&graph_sum[g * H_ + lane], pool);
}

// ---------------- pooled emb -> answering head -> softmax ----------------
__global__ __launch_bounds__(64) void k_final(const float* __restrict__ graph_sum,
                                              const float* __restrict__ tok_sum,
                                              const void* __restrict__ Wa,
                                              const void* __restrict__ ba,
                                              const int* __restrict__ flag,
                                              void* __restrict__ out) {
    int bf = *flag;
    int b = blockIdx.x, l = threadIdx.x;
    float e = (tok_sum[l] + graph_sum[b * H_ + l]) * (1.0f / 1034.0f);
    float p0 = e * ld1(Wa, l * 2 + 0, bf);
    float p1 = e * ld1(Wa, l * 2 + 1, bf);
#pragma unroll
    for (int d = 32; d >= 1; d >>= 1) {
        p0 += __shfl_xor(p0, d);
        p1 += __shfl_xor(p1, d);
    }
    if (l == 0) {
        float l0 = p0 + ld1(ba, 0, bf);
        float l1 = p1 + ld1(ba, 1, bf);
        float mx = fmaxf(l0, l1);
        float e0 = expf(l0 - mx), e1 = expf(l1 - mx);
        float s = e0 + e1;
        float o0 = e0 / s, o1 = e1 / s;
        if (bf) {
            ((__hip_bfloat16*)out)[b * 2 + 0] = __float2bfloat16(o0);
            ((__hip_bfloat16*)out)[b * 2 + 1] = __float2bfloat16(o1);
        } else {
            ((float*)out)[b * 2 + 0] = o0;
            ((float*)out)[b * 2 + 1] = o1;
        }
    }
}

extern "C" void kernel_launch(void* const* d_in, const int* in_sizes, int n_in,
                              void* d_out, int out_size, void* d_ws, size_t ws_size,
                              hipStream_t stream) {
    (void)in_sizes; (void)n_in; (void)out_size; (void)ws_size;
    const void* x      = d_in[0];
    const void* tokens = d_in[1];
    const void* W1     = d_in[2];
    const void* b1     = d_in[3];
    const void* W2     = d_in[4];
    const void* b2     = d_in[5];
    const void* Wa     = d_in[6];
    const void* ba     = d_in[7];
    const int* esrc = (const int*)d_in[8];
    const int* edst = (const int*)d_in[9];

    char* w = (char*)d_ws;
    auto alloc = [&](size_t bytes) { void* p = (void*)w; w += (bytes + 255) & ~(size_t)255; return p; };
    int*      in_deg    = (int*)alloc(BN * 4);
    int*      offs      = (int*)alloc((BN + 1) * 4);
    int*      cursor    = (int*)alloc(BN * 4);
    int*      csr       = (int*)alloc(BE * 4);
    int*      maskA     = (int*)alloc(BN * 4);
    float*    inv_s     = (float*)alloc(BN * 4);
    uint32_t* y1        = (uint32_t*)alloc((size_t)(BN + 1) * 32 * 4);  // packed bf16 pairs
    uint32_t* y2        = (uint32_t*)alloc((size_t)(BN + 1) * 32 * 4);
    float*    P1        = (float*)alloc(T_ * H_ * 4);
    float*    P2        = (float*)alloc(T_ * H_ * 4);
    float*    tok_sum   = (float*)alloc(H_ * 4);
    float*    graph_sum = (float*)alloc(B_ * H_ * 4);
    short8*   Bfr       = (short8*)alloc(4 * 5 * 64 * sizeof(short8));
    int*      dflag     = (int*)alloc(256);

    hipMemsetAsync(in_deg, 0, BN * 4, stream);
    hipMemsetAsync(graph_sum, 0, B_ * H_ * 4, stream);
    hipMemsetAsync(y1 + (size_t)BN * 32, 0, 128, stream);   // zero row (odd-degree pad)
    hipMemsetAsync(y2 + (size_t)BN * 32, 0, 128, stream);

    k_detect   <<<1, 64, 0, stream>>>(tokens, dflag);
    k_deg      <<<BE / 256, 256, 0, stream>>>(edst, in_deg);
    k_prep     <<<5, 256, 0, stream>>>(W1, tokens, dflag, Bfr);
    k_tok      <<<1, 64, 0, stream>>>(tokens, W1, b1, W2, b2, dflag, P1, P2, tok_sum);
    k_scan     <<<1, 1024, 0, stream>>>(in_deg, offs, cursor);
    k_fill     <<<BE / 256, 256, 0, stream>>>(esrc, edst, cursor, csr);
    k_node_mfma<<<BN / 64, 256, 0, stream>>>(x, Bfr, in_deg, dflag, y1, inv_s, maskA);
    k_layer1   <<<BN / 16, 256, 0, stream>>>(y1, inv_s, maskA, offs, csr, P1, b1, W2, dflag, y2);
    k_layer2   <<<BN / 64, 256, 0, stream>>>(y2, inv_s, maskA, offs, csr, P2, b2, dflag, graph_sum);
    k_final    <<<B_, 64, 0, stream>>>(graph_sum, tok_sum, Wa, ba, dflag, d_out);
}

// Round 5
// 338.129 us; speedup vs baseline: 2.2480x; 1.2345x over previous
//
#include <hip/hip_runtime.h>
#include <hip/hip_bf16.h>
#include <stdint.h>

#define B_ 64
#define N_ 1024
#define E_ 16384
#define F_ 128
#define H_ 64
#define T_ 10
#define BN (B_*N_)   // 65536
#define BE (B_*E_)   // 1048576

// sigmoid(z) >= p  <=>  z >= log(p/(1-p))
#define TH_INNER (-0.84729786f)   // logit(0.3)
#define TH_CROSS (-2.1972246f)    // logit(0.1)

typedef __attribute__((ext_vector_type(8))) short short8;  // bf16x8 MFMA frag
typedef __attribute__((ext_vector_type(4))) float f32x4;   // MFMA acc

// ---- dtype-agnostic loads: bf=1 -> packed bf16, bf=0 -> float32 ----
__device__ __forceinline__ float ld1(const void* p, int i, int bf) {
    if (bf) {
        uint16_t u = ((const uint16_t*)p)[i];
        return __uint_as_float(((uint32_t)u) << 16);
    }
    return ((const float*)p)[i];
}

__device__ __forceinline__ short to_bf(float x) {
    return (short)__bfloat16_as_ushort(__float2bfloat16(x));
}

__device__ __forceinline__ uint32_t pack_bf2(float lo, float hi) {
    uint32_t l = (uint32_t)__bfloat16_as_ushort(__float2bfloat16(lo));
    uint32_t h = (uint32_t)__bfloat16_as_ushort(__float2bfloat16(hi));
    return l | (h << 16);
}

__device__ __forceinline__ float bflo(uint32_t u) { return __uint_as_float(u << 16); }
__device__ __forceinline__ float bfhi(uint32_t u) { return __uint_as_float(u & 0xffff0000u); }

// ---------------- dtype detection (1 wave) ----------------
__global__ __launch_bounds__(64) void k_detect(const void* __restrict__ tokens,
                                               int* __restrict__ flag) {
    int l = threadIdx.x;
    uint32_t u = ((const uint32_t*)tokens)[l];
    float lo = __uint_as_float(u << 16);
    int ok = (fabsf(lo) <= 1.0f) ? 1 : 0;   // NaN -> 0
    unsigned long long vote = __ballot(ok);
    if (l == 0) *flag = (vote == ~0ull) ? 1 : 0;
}

// ---------------- in-degree via atomics ----------------
__global__ __launch_bounds__(256) void k_deg(const int* __restrict__ dst,
                                             int* __restrict__ in_deg) {
    int i = blockIdx.x * 256 + threadIdx.x;
    int b = i >> 14;                             // E_ = 2^14
    atomicAdd(&in_deg[b * N_ + dst[i]], 1);
}

// ---------------- exclusive scan (single block) ----------------
__global__ __launch_bounds__(1024) void k_scan(const int* __restrict__ in_deg,
                                               int* __restrict__ offs,
                                               int* __restrict__ cursor) {
    __shared__ int sums[1024];
    int t = threadIdx.x;
    int base = t * 64;
    int s = 0;
    for (int i = 0; i < 64; ++i) s += in_deg[base + i];
    sums[t] = s;
    __syncthreads();
    for (int d = 1; d < 1024; d <<= 1) {
        int v = (t >= d) ? sums[t - d] : 0;
        __syncthreads();
        sums[t] += v;
        __syncthreads();
    }
    int start = (t == 0) ? 0 : sums[t - 1];
    for (int i = 0; i < 64; ++i) {
        int v = in_deg[base + i];
        offs[base + i] = start;
        cursor[base + i] = start;
        start += v;
    }
    if (t == 1023) offs[BN] = start;
}

// ---------------- CSR fill ----------------
__global__ __launch_bounds__(256) void k_fill(const int* __restrict__ src,
                                              const int* __restrict__ dst,
                                              int* __restrict__ cursor,
                                              int* __restrict__ csr) {
    int i = blockIdx.x * 256 + threadIdx.x;
    int b = i >> 14;
    int d = b * N_ + dst[i];
    int p = atomicAdd(&cursor[d], 1);
    csr[p] = b * N_ + src[i];
}

// ---------------- build swizzled B fragments for node GEMM (W1|tokens^T) ----------------
__global__ __launch_bounds__(256) void k_prep(const void* __restrict__ W1,
                                              const void* __restrict__ tokens,
                                              const int* __restrict__ flag,
                                              short8* __restrict__ Bfr) {
    int bf = *flag;
    int f = blockIdx.x * 256 + threadIdx.x;      // [0, 1280)
    int c = f / 320, rem = f % 320;
    int nt = rem / 64, lane = rem % 64;
    int q = lane >> 4, n = nt * 16 + (lane & 15);
    int k0 = c * 32 + q * 8;
    short8 v;
#pragma unroll
    for (int j = 0; j < 8; ++j) {
        int k = k0 + j;
        float x = 0.f;
        if (n < H_) x = ld1(W1, k * H_ + n, bf);
        else if (n < H_ + T_) x = ld1(tokens, (n - H_) * F_ + k, bf);
        v[j] = to_bf(x);
    }
    Bfr[f] = v;
}

// ---------------- W2 fragments for the h1@W2 GEMM ----------------
__global__ __launch_bounds__(256) void k_prep2(const void* __restrict__ W2,
                                               const int* __restrict__ flag,
                                               short8* __restrict__ Bfr2) {
    int bf = *flag;
    int f = blockIdx.x * 256 + threadIdx.x;      // [0, 512)
    int c = f / 256, rem = f % 256;
    int nt = rem / 64, lane = rem % 64;
    int q = lane >> 4, n = nt * 16 + (lane & 15);
    int k0 = c * 32 + q * 8;
    short8 v;
#pragma unroll
    for (int j = 0; j < 8; ++j) v[j] = to_bf(ld1(W2, (k0 + j) * H_ + n, bf));
    Bfr2[f] = v;
}

// ---------------- token stream (graph-independent), one block of 64 ----------------
__global__ __launch_bounds__(64) void k_tok(const void* __restrict__ tokens,
                                            const void* __restrict__ W1,
                                            const void* __restrict__ b1,
                                            const void* __restrict__ W2,
                                            const void* __restrict__ b2,
                                            const int* __restrict__ flag,
                                            float* __restrict__ P1,
                                            float* __restrict__ P2,
                                            float* __restrict__ tok_sum) {
    __shared__ float tk[T_ * F_], w1[F_ * H_], w2[H_ * H_];
    __shared__ float Min[T_ * T_], ist[T_], idt[T_], h1s[T_ * H_];
    int bf = *flag;
    int l = threadIdx.x;
    for (int i = l; i < T_ * F_; i += 64) tk[i] = ld1(tokens, i, bf);
    for (int i = l; i < F_ * H_; i += 64) w1[i] = ld1(W1, i, bf);
    for (int i = l; i < H_ * H_; i += 64) w2[i] = ld1(W2, i, bf);
    __syncthreads();
    for (int p = l; p < T_ * T_; p += 64) {
        int i = p / T_, j = p % T_;
        float s = 0.f;
        for (int f = 0; f < F_; ++f) s += tk[i * F_ + f] * tk[j * F_ + f];
        Min[p] = (s >= TH_INNER) ? 1.f : 0.f;
    }
    __syncthreads();
    if (l < T_) {
        float d = 1.f;
        for (int s = 0; s < T_; ++s) d += Min[s * T_ + l];
        ist[l] = 1.f / sqrtf(d);
        idt[l] = 1.f / d;
    }
    __syncthreads();
    float ht1[T_];
    for (int t = 0; t < T_; ++t) {
        float a = 0.f;
        for (int f = 0; f < F_; ++f) a += tk[t * F_ + f] * w1[f * H_ + l];
        ht1[t] = a;
    }
    float b1f = ld1(b1, l, bf);
    for (int t = 0; t < T_; ++t) {
        float a = ht1[t] * idt[t] + b1f;
        for (int s = 0; s < T_; ++s) a += Min[t * T_ + s] * ist[t] * ist[s] * ht1[s];
        a = (a >= 0.f) ? a : 0.01f * a;
        h1s[t * H_ + l] = a;
        P1[t * H_ + l] = ist[t] * ht1[t];
    }
    __syncthreads();
    float ht2[T_];
    for (int t = 0; t < T_; ++t) {
        float a = 0.f;
        for (int k = 0; k < H_; ++k) a += h1s[t * H_ + k] * w2[k * H_ + l];
        ht2[t] = a;
        P2[t * H_ + l] = ist[t] * a;
    }
    float b2f = ld1(b2, l, bf);
    float ts = 0.f;
    for (int t = 0; t < T_; ++t) {
        float o = ht2[t] * idt[t] + b2f;
        for (int s = 0; s < T_; ++s) o += Min[t * T_ + s] * ist[t] * ist[s] * ht2[s];
        ts += o;
    }
    tok_sum[l] = ts;
}

// ---------------- node GEMM via MFMA: y1(bf16 packed) + cross masks + inv_s ----------------
__global__ __launch_bounds__(256) void k_node_mfma(const void* __restrict__ x,
                                                   const short8* __restrict__ Bfr,
                                                   const int* __restrict__ in_deg,
                                                   const int* __restrict__ flag,
                                                   uint32_t* __restrict__ y1,
                                                   float* __restrict__ inv_s,
                                                   int* __restrict__ maskA) {
    int bf = *flag;
    int tid = threadIdx.x;
    int lane = tid & 63, wv = tid >> 6;
    int g = blockIdx.x & 63, c = blockIdx.x >> 6;   // XCD swizzle: graph -> XCD g%8
    int row0 = g * N_ + c * 64 + wv * 16;
    int m = lane & 15, q = lane >> 4;
    int row = row0 + m;
    short8 afr[4];
    if (bf) {
        const short8* ar = (const short8*)((const uint16_t*)x + (size_t)row * F_);
#pragma unroll
        for (int cc = 0; cc < 4; ++cc) afr[cc] = ar[cc * 4 + q];
    } else {
        const float* ar = (const float*)x + (size_t)row * F_;
#pragma unroll
        for (int cc = 0; cc < 4; ++cc)
#pragma unroll
            for (int j = 0; j < 8; ++j)
                afr[cc][j] = to_bf(ar[cc * 32 + q * 8 + j]);
    }
    f32x4 acc[5] = {};
#pragma unroll
    for (int nt = 0; nt < 5; ++nt)
#pragma unroll
        for (int cc = 0; cc < 4; ++cc) {
            short8 bfr = Bfr[(cc * 5 + nt) * 64 + lane];
            acc[nt] = __builtin_amdgcn_mfma_f32_16x16x32_bf16(afr[cc], bfr, acc[nt], 0, 0, 0);
        }
    unsigned long long bal[4];
#pragma unroll
    for (int r = 0; r < 4; ++r) {
        int pred = (m < T_) && (acc[4][r] >= TH_CROSS);
        bal[r] = __ballot(pred);
    }
    float isv[4];
#pragma unroll
    for (int r = 0; r < 4; ++r) {
        int node = row0 + q * 4 + r;
        int mask = (int)((bal[r] >> (q * 16)) & 0x3FF);
        float deg = 1.f + (float)in_deg[node] + (float)__popc((unsigned)mask);
        isv[r] = 1.f / sqrtf(deg);
        if (m == 0) { inv_s[node] = isv[r]; maskA[node] = mask; }
    }
#pragma unroll
    for (int r = 0; r < 4; ++r) {
        int node = row0 + q * 4 + r;
#pragma unroll
        for (int nt = 0; nt < 4; ++nt) {
            float v = acc[nt][r] * isv[r];
            float vh = __shfl(v, lane + 1);
            if ((m & 1) == 0)
                y1[(size_t)node * 32 + nt * 8 + (m >> 1)] = pack_bf2(v, vh);
        }
    }
}

// ---------------- lean pair-domain gather: 8 nodes/wave, ILP=8, idx prefetch ----------------
// Accumulates neighbor rows + self row of `node` into (aLo, aHi) in pair domain.
struct GatherState { int idx; };   // current node's first index batch (prefetched)

__device__ __forceinline__ void gather_node(const uint32_t* __restrict__ yu,
                                            const int* __restrict__ csr,
                                            int idx_cur, int beg, int cnt,
                                            int node, int h, int fp, int lane,
                                            float& aLo, float& aHi) {
    float lo = 0.f, hi = 0.f;
    int eb = 0;
    while (true) {
        int cbat = min(cnt - eb, 64);
        int np = (cbat + 1) >> 1;
        for (int p = 0; p < np; p += 8) {
            int s[8];
#pragma unroll
            for (int j = 0; j < 8; ++j) {
                int e = 2 * (p + j) + h;
                int sv = __shfl(idx_cur, e & 63);
                s[j] = (e < cbat) ? sv : BN;     // BN = zero row
            }
            uint32_t u[8];
#pragma unroll
            for (int j = 0; j < 8; ++j) u[j] = yu[(size_t)s[j] * 32 + fp];
#pragma unroll
            for (int j = 0; j < 8; ++j) { lo += bflo(u[j]); hi += bfhi(u[j]); }
        }
        eb += 64;
        if (eb >= cnt) break;
        idx_cur = csr[beg + eb + lane];          // rare (deg > 64)
    }
    lo += __shfl_xor(lo, 32);
    hi += __shfl_xor(hi, 32);
    uint32_t su = yu[(size_t)node * 32 + fp];    // self row
    aLo = lo + bflo(su);
    aHi = hi + bfhi(su);
}

// ---------------- layer1: gather y1 + epilogue -> h1 (bf16 packed) ----------------
__global__ __launch_bounds__(256, 6) void k_layer1(const uint32_t* __restrict__ y1,
                                                   const float* __restrict__ inv_s,
                                                   const int* __restrict__ maskA,
                                                   const int* __restrict__ offs,
                                                   const int* __restrict__ csr,
                                                   const float* __restrict__ P1,
                                                   const void* __restrict__ b1,
                                                   const int* __restrict__ flag,
                                                   uint32_t* __restrict__ h1) {
    __shared__ float2 p1p[T_ * 32];
    int bf = *flag;
    int tid = threadIdx.x;
    for (int i = tid; i < T_ * 32; i += 256) {
        int t = i >> 5, fp = i & 31;
        p1p[i] = make_float2(P1[t * H_ + 2 * fp], P1[t * H_ + 2 * fp + 1]);
    }
    __syncthreads();
    int lane = tid & 63, wv = tid >> 6;
    int h = lane >> 5, fp = lane & 31;
    int g = blockIdx.x & 63, c = blockIdx.x >> 6;   // c in [0,32)
    int nbase = g * N_ + c * 32 + wv * 8;
    int offv = offs[nbase + min(lane, 8)];
    float isv = inv_s[nbase + (lane & 7)];
    int maskv = maskA[nbase + (lane & 7)];
    float b1lo = ld1(b1, 2 * fp, bf), b1hi = ld1(b1, 2 * fp + 1, bf);
    int idx = csr[__shfl(offv, 0) + lane];           // prefetch node 0
    for (int i = 0; i < 8; ++i) {
        int beg = __shfl(offv, i), end = __shfl(offv, i + 1);
        int cnt = end - beg;
        int idx_cur = idx;
        if (i < 7) idx = csr[end + lane];            // prefetch next node
        int node = nbase + i;
        float aLo, aHi;
        gather_node(y1, csr, idx_cur, beg, cnt, node, h, fp, lane, aLo, aHi);
        int mask = __shfl(maskv, i);
        float is = __shfl(isv, i);
#pragma unroll
        for (int t = 0; t < T_; ++t)
            if (mask & (1 << t)) { float2 pv = p1p[t * 32 + fp]; aLo += pv.x; aHi += pv.y; }
        float hLo = aLo * is + b1lo;
        float hHi = aHi * is + b1hi;
        hLo = (hLo >= 0.f) ? hLo : 0.01f * hLo;
        hHi = (hHi >= 0.f) ? hHi : 0.01f * hHi;
        if (h == 0) h1[(size_t)node * 32 + fp] = pack_bf2(hLo, hHi);
    }
}

// ---------------- h1 @ W2 via MFMA -> y2 (scaled by inv_s, bf16 packed) ----------------
__global__ __launch_bounds__(256) void k_gemm(const uint32_t* __restrict__ h1,
                                              const short8* __restrict__ Bfr2,
                                              const float* __restrict__ inv_s,
                                              uint32_t* __restrict__ y2) {
    int tid = threadIdx.x;
    int lane = tid & 63, wv = tid >> 6;
    int g = blockIdx.x & 63, c = blockIdx.x >> 6;   // c in [0,16)
    int row0 = g * N_ + c * 64 + wv * 16;
    int m = lane & 15, q = lane >> 4;
    const short8* ar = (const short8*)(h1 + (size_t)(row0 + m) * 32);
    short8 afr[2];
#pragma unroll
    for (int cc = 0; cc < 2; ++cc) afr[cc] = ar[cc * 4 + q];
    f32x4 acc[4] = {};
#pragma unroll
    for (int nt = 0; nt < 4; ++nt)
#pragma unroll
        for (int cc = 0; cc < 2; ++cc) {
            short8 bfr = Bfr2[(cc * 4 + nt) * 64 + lane];
            acc[nt] = __builtin_amdgcn_mfma_f32_16x16x32_bf16(afr[cc], bfr, acc[nt], 0, 0, 0);
        }
    float isv[4];
#pragma unroll
    for (int r = 0; r < 4; ++r) isv[r] = inv_s[row0 + q * 4 + r];
#pragma unroll
    for (int r = 0; r < 4; ++r) {
        int node = row0 + q * 4 + r;
#pragma unroll
        for (int nt = 0; nt < 4; ++nt) {
            float v = acc[nt][r] * isv[r];
            float vh = __shfl(v, lane + 1);
            if ((m & 1) == 0)
                y2[(size_t)node * 32 + nt * 8 + (m >> 1)] = pack_bf2(v, vh);
        }
    }
}

// ---------------- layer2: gather y2 + pooling epilogue ----------------
__global__ __launch_bounds__(256, 6) void k_layer2(const uint32_t* __restrict__ y2,
                                                   const float* __restrict__ inv_s,
                                                   const int* __restrict__ maskA,
                                                   const int* __restrict__ offs,
                                                   const int* __restrict__ csr,
                                                   const float* __restrict__ P2,
                                                   const void* __restrict__ b2,
                                                   const int* __restrict__ flag,
                                                   float* __restrict__ graph_sum) {
    __shared__ float2 p2p[T_ * 32];
    int bf = *flag;
    int tid = threadIdx.x;
    for (int i = tid; i < T_ * 32; i += 256) {
        int t = i >> 5, fp = i & 31;
        p2p[i] = make_float2(P2[t * H_ + 2 * fp], P2[t * H_ + 2 * fp + 1]);
    }
    __syncthreads();
    int lane = tid & 63, wv = tid >> 6;
    int h = lane >> 5, fp = lane & 31;
    int g = blockIdx.x & 63, c = blockIdx.x >> 6;   // c in [0,32)
    int nbase = g * N_ + c * 32 + wv * 8;
    int offv = offs[nbase + min(lane, 8)];
    float isv = inv_s[nbase + (lane & 7)];
    int maskv = maskA[nbase + (lane & 7)];
    float b2lo = ld1(b2, 2 * fp, bf), b2hi = ld1(b2, 2 * fp + 1, bf);
    int idx = csr[__shfl(offv, 0) + lane];
    float poolLo = 0.f, poolHi = 0.f;
    for (int i = 0; i < 8; ++i) {
        int beg = __shfl(offv, i), end = __shfl(offv, i + 1);
        int cnt = end - beg;
        int idx_cur = idx;
        if (i < 7) idx = csr[end + lane];
        int node = nbase + i;
        float aLo, aHi;
        gather_node(y2, csr, idx_cur, beg, cnt, node, h, fp, lane, aLo, aHi);
        int mask = __shfl(maskv, i);
        float is = __shfl(isv, i);
#pragma unroll
        for (int t = 0; t < T_; ++t)
            if (mask & (1 << t)) { float2 pv = p2p[t * 32 + fp]; aLo += pv.x; aHi += pv.y; }
        poolLo += aLo * is + b2lo;
        poolHi += aHi * is + b2hi;
    }
    if (h == 0) {
        atomicAdd(&graph_sum[g * H_ + 2 * fp], poolLo);
        atomicAdd(&graph_sum[g * H_ + 2 * fp + 1], poolHi);
    }
}

// ---------------- pooled emb -> answering head -> softmax ----------------
__global__ __launch_bounds__(64) void k_final(const float* __restrict__ graph_sum,
                                              const float* __restrict__ tok_sum,
                                              const void* __restrict__ Wa,
                                              const void* __restrict__ ba,
                                              const int* __restrict__ flag,
                                              void* __restrict__ out) {
    int bf = *flag;
    int b = blockIdx.x, l = threadIdx.x;
    float e = (tok_sum[l] + graph_sum[b * H_ + l]) * (1.0f / 1034.0f);
    float p0 = e * ld1(Wa, l * 2 + 0, bf);
    float p1 = e * ld1(Wa, l * 2 + 1, bf);
#pragma unroll
    for (int d = 32; d >= 1; d >>= 1) {
        p0 += __shfl_xor(p0, d);
        p1 += __shfl_xor(p1, d);
    }
    if (l == 0) {
        float l0 = p0 + ld1(ba, 0, bf);
        float l1 = p1 + ld1(ba, 1, bf);
        float mx = fmaxf(l0, l1);
        float e0 = expf(l0 - mx), e1 = expf(l1 - mx);
        float s = e0 + e1;
        float o0 = e0 / s, o1 = e1 / s;
        if (bf) {
            ((__hip_bfloat16*)out)[b * 2 + 0] = __float2bfloat16(o0);
            ((__hip_bfloat16*)out)[b * 2 + 1] = __float2bfloat16(o1);
        } else {
            ((float*)out)[b * 2 + 0] = o0;
            ((float*)out)[b * 2 + 1] = o1;
        }
    }
}

extern "C" void kernel_launch(void* const* d_in, const int* in_sizes, int n_in,
                              void* d_out, int out_size, void* d_ws, size_t ws_size,
                              hipStream_t stream) {
    (void)in_sizes; (void)n_in; (void)out_size; (void)ws_size;
    const void* x      = d_in[0];
    const void* tokens = d_in[1];
    const void* W1     = d_in[2];
    const void* b1     = d_in[3];
    const void* W2     = d_in[4];
    const void* b2     = d_in[5];
    const void* Wa     = d_in[6];
    const void* ba     = d_in[7];
    const int* esrc = (const int*)d_in[8];
    const int* edst = (const int*)d_in[9];

    char* w = (char*)d_ws;
    auto alloc = [&](size_t bytes) { void* p = (void*)w; w += (bytes + 255) & ~(size_t)255; return p; };
    int*      in_deg    = (int*)alloc(BN * 4);
    int*      offs      = (int*)alloc((BN + 1) * 4);
    int*      cursor    = (int*)alloc(BN * 4);
    int*      csr       = (int*)alloc(BE * 4 + 256);                   // +64-int pad for prefetch
    int*      maskA     = (int*)alloc(BN * 4);
    float*    inv_s     = (float*)alloc(BN * 4);
    uint32_t* y1        = (uint32_t*)alloc((size_t)(BN + 1) * 32 * 4); // packed bf16 pairs
    uint32_t* h1        = (uint32_t*)alloc((size_t)(BN + 1) * 32 * 4);
    uint32_t* y2        = (uint32_t*)alloc((size_t)(BN + 1) * 32 * 4);
    float*    P1        = (float*)alloc(T_ * H_ * 4);
    float*    P2        = (float*)alloc(T_ * H_ * 4);
    float*    tok_sum   = (float*)alloc(H_ * 4);
    float*    graph_sum = (float*)alloc(B_ * H_ * 4);
    short8*   Bfr       = (short8*)alloc(4 * 5 * 64 * sizeof(short8));
    short8*   Bfr2      = (short8*)alloc(2 * 4 * 64 * sizeof(short8));
    int*      dflag     = (int*)alloc(256);

    hipMemsetAsync(in_deg, 0, BN * 4, stream);
    hipMemsetAsync(graph_sum, 0, B_ * H_ * 4, stream);
    hipMemsetAsync(y1 + (size_t)BN * 32, 0, 128, stream);   // zero rows (gather padding)
    hipMemsetAsync(h1 + (size_t)BN * 32, 0, 128, stream);
    hipMemsetAsync(y2 + (size_t)BN * 32, 0, 128, stream);

    k_detect   <<<1, 64, 0, stream>>>(tokens, dflag);
    k_deg      <<<BE / 256, 256, 0, stream>>>(edst, in_deg);
    k_prep     <<<5, 256, 0, stream>>>(W1, tokens, dflag, Bfr);
    k_prep2    <<<2, 256, 0, stream>>>(W2, dflag, Bfr2);
    k_tok      <<<1, 64, 0, stream>>>(tokens, W1, b1, W2, b2, dflag, P1, P2, tok_sum);
    k_scan     <<<1, 1024, 0, stream>>>(in_deg, offs, cursor);
    k_fill     <<<BE / 256, 256, 0, stream>>>(esrc, edst, cursor, csr);
    k_node_mfma<<<BN / 64, 256, 0, stream>>>(x, Bfr, in_deg, dflag, y1, inv_s, maskA);
    k_layer1   <<<BN / 32, 256, 0, stream>>>(y1, inv_s, maskA, offs, csr, P1, b1, dflag, h1);
    k_gemm     <<<BN / 64, 256, 0, stream>>>(h1, Bfr2, inv_s, y2);
    k_layer2   <<<BN / 32, 256, 0, stream>>>(y2, inv_s, maskA, offs, csr, P2, b2, dflag, graph_sum);
    k_final    <<<B_, 64, 0, stream>>>(graph_sum, tok_sum, Wa, ba, dflag, d_out);
}

// Round 6
// 287.014 us; speedup vs baseline: 2.6483x; 1.1781x over previous
//
#include <hip/hip_runtime.h>
#include <hip/hip_bf16.h>
#include <stdint.h>

#define B_ 64
#define N_ 1024
#define E_ 16384
#define F_ 128
#define H_ 64
#define T_ 10
#define BN (B_*N_)   // 65536
#define BE (B_*E_)   // 1048576

// sigmoid(z) >= p  <=>  z >= log(p/(1-p))
#define TH_INNER (-0.84729786f)   // logit(0.3)
#define TH_CROSS (-2.1972246f)    // logit(0.1)

typedef __attribute__((ext_vector_type(8))) short short8;  // bf16x8 MFMA frag
typedef __attribute__((ext_vector_type(4))) float f32x4;   // MFMA acc

// ---- dtype-agnostic loads: bf=1 -> packed bf16, bf=0 -> float32 ----
__device__ __forceinline__ float ld1(const void* p, int i, int bf) {
    if (bf) {
        uint16_t u = ((const uint16_t*)p)[i];
        return __uint_as_float(((uint32_t)u) << 16);
    }
    return ((const float*)p)[i];
}

__device__ __forceinline__ short to_bf(float x) {
    return (short)__bfloat16_as_ushort(__float2bfloat16(x));
}

__device__ __forceinline__ uint32_t pack_bf2(float lo, float hi) {
    uint32_t l = (uint32_t)__bfloat16_as_ushort(__float2bfloat16(lo));
    uint32_t h = (uint32_t)__bfloat16_as_ushort(__float2bfloat16(hi));
    return l | (h << 16);
}

__device__ __forceinline__ float bflo(uint32_t u) { return __uint_as_float(u << 16); }
__device__ __forceinline__ float bfhi(uint32_t u) { return __uint_as_float(u & 0xffff0000u); }

// ---------------- in-degree via atomics ----------------
__global__ __launch_bounds__(256) void k_deg(const int* __restrict__ dst,
                                             int* __restrict__ in_deg) {
    int i = blockIdx.x * 256 + threadIdx.x;
    int b = i >> 14;                             // E_ = 2^14
    atomicAdd(&in_deg[b * N_ + dst[i]], 1);
}

// ---------------- exclusive scan (single block) ----------------
__global__ __launch_bounds__(1024) void k_scan(const int* __restrict__ in_deg,
                                               int* __restrict__ offs,
                                               int* __restrict__ cursor) {
    __shared__ int sums[1024];
    int t = threadIdx.x;
    int base = t * 64;
    int s = 0;
    for (int i = 0; i < 64; ++i) s += in_deg[base + i];
    sums[t] = s;
    __syncthreads();
    for (int d = 1; d < 1024; d <<= 1) {
        int v = (t >= d) ? sums[t - d] : 0;
        __syncthreads();
        sums[t] += v;
        __syncthreads();
    }
    int start = (t == 0) ? 0 : sums[t - 1];
    for (int i = 0; i < 64; ++i) {
        int v = in_deg[base + i];
        offs[base + i] = start;
        cursor[base + i] = start;
        start += v;
    }
    if (t == 1023) offs[BN] = start;
}

// ---------------- CSR fill ----------------
__global__ __launch_bounds__(256) void k_fill(const int* __restrict__ src,
                                              const int* __restrict__ dst,
                                              int* __restrict__ cursor,
                                              int* __restrict__ csr) {
    int i = blockIdx.x * 256 + threadIdx.x;
    int b = i >> 14;
    int d = b * N_ + dst[i];
    int p = atomicAdd(&cursor[d], 1);
    csr[p] = b * N_ + src[i];
}

// ---------------- build swizzled B fragments (W1 | tokens^T) + publish dtype flag ----------------
__global__ __launch_bounds__(256) void k_prep(const void* __restrict__ W1,
                                              const void* __restrict__ tokens,
                                              int* __restrict__ flag,
                                              short8* __restrict__ Bfr) {
    // local dtype detection (every wave derives the same verdict)
    uint32_t du = ((const uint32_t*)tokens)[threadIdx.x & 63];
    float dlo = __uint_as_float(du << 16);
    unsigned long long vote = __ballot(fabsf(dlo) <= 1.0f);
    int bf = (vote == ~0ull) ? 1 : 0;
    if (blockIdx.x == 0 && threadIdx.x == 0) *flag = bf;

    int f = blockIdx.x * 256 + threadIdx.x;      // [0, 1280)
    int c = f / 320, rem = f % 320;
    int nt = rem / 64, lane = rem % 64;
    int q = lane >> 4, n = nt * 16 + (lane & 15);
    int k0 = c * 32 + q * 8;
    short8 v;
#pragma unroll
    for (int j = 0; j < 8; ++j) {
        int k = k0 + j;
        float x = 0.f;
        if (n < H_) x = ld1(W1, k * H_ + n, bf);
        else if (n < H_ + T_) x = ld1(tokens, (n - H_) * F_ + k, bf);
        v[j] = to_bf(x);
    }
    Bfr[f] = v;
}

// ---------------- W2 fragments for the h1@W2 GEMM ----------------
__global__ __launch_bounds__(256) void k_prep2(const void* __restrict__ W2,
                                               const int* __restrict__ flag,
                                               short8* __restrict__ Bfr2) {
    int bf = *flag;
    int f = blockIdx.x * 256 + threadIdx.x;      // [0, 512)
    int c = f / 256, rem = f % 256;
    int nt = rem / 64, lane = rem % 64;
    int q = lane >> 4, n = nt * 16 + (lane & 15);
    int k0 = c * 32 + q * 8;
    short8 v;
#pragma unroll
    for (int j = 0; j < 8; ++j) v[j] = to_bf(ld1(W2, (k0 + j) * H_ + n, bf));
    Bfr2[f] = v;
}

// ---------------- token stream via MFMA (1 wave) ----------------
// M_in = tokens@tokens^T (Bfr nt=4), ht1 = tokens@W1 (Bfr nt=0..3), ht2 = h1@W2 (Bfr2).
__global__ __launch_bounds__(64) void k_tok(const void* __restrict__ tokens,
                                            const void* __restrict__ b1,
                                            const void* __restrict__ b2,
                                            const short8* __restrict__ Bfr,
                                            const short8* __restrict__ Bfr2,
                                            const int* __restrict__ flag,
                                            float* __restrict__ P1,
                                            float* __restrict__ P2,
                                            float* __restrict__ tok_sum) {
    __shared__ float nm[T_ * 16];       // normMin[t][s] = Min*ist_t*ist_s
    __shared__ float ist_s[16], idt_s[16];
    __shared__ float htbuf[T_ * 64];    // ht1, later reused for ht2
    __shared__ float h1s[T_ * 64];
    int bf = *flag;
    int l = threadIdx.x;
    int m = l & 15, q = l >> 4;
    int mrow = (m < T_) ? m : (T_ - 1);          // clamp: rows >=10 duplicate row 9 (masked later)
    // A fragments: tokens rows
    short8 afr[4];
    if (bf) {
        const short8* ar = (const short8*)((const uint16_t*)tokens + mrow * F_);
#pragma unroll
        for (int c = 0; c < 4; ++c) afr[c] = ar[c * 4 + q];
    } else {
        const float* ar = (const float*)tokens + mrow * F_;
#pragma unroll
        for (int c = 0; c < 4; ++c)
#pragma unroll
            for (int j = 0; j < 8; ++j) afr[c][j] = to_bf(ar[c * 32 + q * 8 + j]);
    }
    f32x4 accM = {};
    f32x4 acc1[4] = {};
#pragma unroll
    for (int c = 0; c < 4; ++c) {
        accM = __builtin_amdgcn_mfma_f32_16x16x32_bf16(afr[c], Bfr[(c * 5 + 4) * 64 + l], accM, 0, 0, 0);
#pragma unroll
        for (int nt = 0; nt < 4; ++nt)
            acc1[nt] = __builtin_amdgcn_mfma_f32_16x16x32_bf16(afr[c], Bfr[(c * 5 + nt) * 64 + l], acc1[nt], 0, 0, 0);
    }
    // deg_tok for column (token) m: count Min over the 16 rows
    int cnt = 0;
#pragma unroll
    for (int r = 0; r < 4; ++r) {
        int row = q * 4 + r;
        if (row < T_ && m < T_ && accM[r] >= TH_INNER) cnt++;
    }
    cnt += __shfl_xor(cnt, 16);
    cnt += __shfl_xor(cnt, 32);
    float deg = 1.f + (float)cnt;
    float istc = 1.f / sqrtf(deg);
    float idtc = 1.f / deg;
    if (q == 0 && m < T_) { ist_s[m] = istc; idt_s[m] = idtc; }
    // ht1 -> LDS
#pragma unroll
    for (int nt = 0; nt < 4; ++nt)
#pragma unroll
        for (int r = 0; r < 4; ++r) {
            int row = q * 4 + r;
            if (row < T_) htbuf[row * 64 + nt * 16 + m] = acc1[nt][r];
        }
    __syncthreads();
    // normMin
    if (m < T_) {
#pragma unroll
        for (int r = 0; r < 4; ++r) {
            int row = q * 4 + r;
            if (row < T_)
                nm[row * 16 + m] = (accM[r] >= TH_INNER) ? ist_s[row] * istc : 0.f;
        }
    }
    __syncthreads();
    // epilogue 1: out_tok1 = norm_in@ht1 + ht1*idt + b1 -> lrelu -> h1
    float htc[T_];
#pragma unroll
    for (int s = 0; s < T_; ++s) htc[s] = htbuf[s * 64 + l];
    float b1f = ld1(b1, l, bf);
#pragma unroll
    for (int t = 0; t < T_; ++t) {
        float a = htc[t] * idt_s[t] + b1f;
#pragma unroll
        for (int s = 0; s < T_; ++s) a += nm[t * 16 + s] * htc[s];
        a = (a >= 0.f) ? a : 0.01f * a;
        h1s[t * 64 + l] = a;
        P1[t * H_ + l] = ist_s[t] * htc[t];
    }
    __syncthreads();
    // ht2 = h1 @ W2
    short8 a2fr[2];
#pragma unroll
    for (int c = 0; c < 2; ++c)
#pragma unroll
        for (int j = 0; j < 8; ++j) a2fr[c][j] = to_bf(h1s[mrow * 64 + c * 32 + q * 8 + j]);
    f32x4 acc2[4] = {};
#pragma unroll
    for (int nt = 0; nt < 4; ++nt)
#pragma unroll
        for (int c = 0; c < 2; ++c)
            acc2[nt] = __builtin_amdgcn_mfma_f32_16x16x32_bf16(a2fr[c], Bfr2[(c * 4 + nt) * 64 + l], acc2[nt], 0, 0, 0);
#pragma unroll
    for (int nt = 0; nt < 4; ++nt)
#pragma unroll
        for (int r = 0; r < 4; ++r) {
            int row = q * 4 + r;
            if (row < T_) htbuf[row * 64 + nt * 16 + m] = acc2[nt][r];
        }
    __syncthreads();
    // epilogue 2: P2 + token pooling sum
    float b2f = ld1(b2, l, bf);
#pragma unroll
    for (int s = 0; s < T_; ++s) htc[s] = htbuf[s * 64 + l];
    float ts = 0.f;
#pragma unroll
    for (int t = 0; t < T_; ++t) {
        float o = htc[t] * idt_s[t] + b2f;
#pragma unroll
        for (int s = 0; s < T_; ++s) o += nm[t * 16 + s] * htc[s];
        ts += o;
        P2[t * H_ + l] = ist_s[t] * htc[t];
    }
    tok_sum[l] = ts;
}

// ---------------- node GEMM via MFMA: y1(bf16 packed) + cross masks + inv_s ----------------
__global__ __launch_bounds__(256) void k_node_mfma(const void* __restrict__ x,
                                                   const short8* __restrict__ Bfr,
                                                   const int* __restrict__ in_deg,
                                                   const int* __restrict__ flag,
                                                   uint32_t* __restrict__ y1,
                                                   float* __restrict__ inv_s,
                                                   int* __restrict__ maskA) {
    int bf = *flag;
    int tid = threadIdx.x;
    int lane = tid & 63, wv = tid >> 6;
    int g = blockIdx.x & 63, c = blockIdx.x >> 6;   // XCD swizzle: graph -> XCD g%8
    int row0 = g * N_ + c * 64 + wv * 16;
    int m = lane & 15, q = lane >> 4;
    int row = row0 + m;
    short8 afr[4];
    if (bf) {
        const short8* ar = (const short8*)((const uint16_t*)x + (size_t)row * F_);
#pragma unroll
        for (int cc = 0; cc < 4; ++cc) afr[cc] = ar[cc * 4 + q];
    } else {
        const float* ar = (const float*)x + (size_t)row * F_;
#pragma unroll
        for (int cc = 0; cc < 4; ++cc)
#pragma unroll
            for (int j = 0; j < 8; ++j)
                afr[cc][j] = to_bf(ar[cc * 32 + q * 8 + j]);
    }
    f32x4 acc[5] = {};
#pragma unroll
    for (int nt = 0; nt < 5; ++nt)
#pragma unroll
        for (int cc = 0; cc < 4; ++cc) {
            short8 bfr = Bfr[(cc * 5 + nt) * 64 + lane];
            acc[nt] = __builtin_amdgcn_mfma_f32_16x16x32_bf16(afr[cc], bfr, acc[nt], 0, 0, 0);
        }
    unsigned long long bal[4];
#pragma unroll
    for (int r = 0; r < 4; ++r) {
        int pred = (m < T_) && (acc[4][r] >= TH_CROSS);
        bal[r] = __ballot(pred);
    }
    float isv[4];
#pragma unroll
    for (int r = 0; r < 4; ++r) {
        int node = row0 + q * 4 + r;
        int mask = (int)((bal[r] >> (q * 16)) & 0x3FF);
        float deg = 1.f + (float)in_deg[node] + (float)__popc((unsigned)mask);
        isv[r] = 1.f / sqrtf(deg);
        if (m == 0) { inv_s[node] = isv[r]; maskA[node] = mask; }
    }
#pragma unroll
    for (int r = 0; r < 4; ++r) {
        int node = row0 + q * 4 + r;
#pragma unroll
        for (int nt = 0; nt < 4; ++nt) {
            float v = acc[nt][r] * isv[r];
            float vh = __shfl(v, lane + 1);
            if ((m & 1) == 0)
                y1[(size_t)node * 32 + nt * 8 + (m >> 1)] = pack_bf2(v, vh);
        }
    }
}

// ---------------- lean pair-domain gather: 8 nodes/wave, ILP=8, idx prefetch ----------------
__device__ __forceinline__ void gather_node(const uint32_t* __restrict__ yu,
                                            const int* __restrict__ csr,
                                            int idx_cur, int beg, int cnt,
                                            int node, int h, int fp, int lane,
                                            float& aLo, float& aHi) {
    float lo = 0.f, hi = 0.f;
    int eb = 0;
    while (true) {
        int cbat = min(cnt - eb, 64);
        int np = (cbat + 1) >> 1;
        for (int p = 0; p < np; p += 8) {
            int s[8];
#pragma unroll
            for (int j = 0; j < 8; ++j) {
                int e = 2 * (p + j) + h;
                int sv = __shfl(idx_cur, e & 63);
                s[j] = (e < cbat) ? sv : BN;     // BN = zero row
            }
            uint32_t u[8];
#pragma unroll
            for (int j = 0; j < 8; ++j) u[j] = yu[(size_t)s[j] * 32 + fp];
#pragma unroll
            for (int j = 0; j < 8; ++j) { lo += bflo(u[j]); hi += bfhi(u[j]); }
        }
        eb += 64;
        if (eb >= cnt) break;
        idx_cur = csr[beg + eb + lane];          // rare (deg > 64)
    }
    lo += __shfl_xor(lo, 32);
    hi += __shfl_xor(hi, 32);
    uint32_t su = yu[(size_t)node * 32 + fp];    // self row
    aLo = lo + bflo(su);
    aHi = hi + bfhi(su);
}

// ---------------- layer1: gather y1 + epilogue -> h1 (bf16 packed) ----------------
__global__ __launch_bounds__(256, 6) void k_layer1(const uint32_t* __restrict__ y1,
                                                   const float* __restrict__ inv_s,
                                                   const int* __restrict__ maskA,
                                                   const int* __restrict__ offs,
                                                   const int* __restrict__ csr,
                                                   const float* __restrict__ P1,
                                                   const void* __restrict__ b1,
                                                   const int* __restrict__ flag,
                                                   uint32_t* __restrict__ h1) {
    __shared__ float2 p1p[T_ * 32];
    int bf = *flag;
    int tid = threadIdx.x;
    for (int i = tid; i < T_ * 32; i += 256) {
        int t = i >> 5, fp = i & 31;
        p1p[i] = make_float2(P1[t * H_ + 2 * fp], P1[t * H_ + 2 * fp + 1]);
    }
    __syncthreads();
    int lane = tid & 63, wv = tid >> 6;
    int h = lane >> 5, fp = lane & 31;
    int g = blockIdx.x & 63, c = blockIdx.x >> 6;   // c in [0,32)
    int nbase = g * N_ + c * 32 + wv * 8;
    int offv = offs[nbase + min(lane, 8)];
    float isv = inv_s[nbase + (lane & 7)];
    int maskv = maskA[nbase + (lane & 7)];
    float b1lo = ld1(b1, 2 * fp, bf), b1hi = ld1(b1, 2 * fp + 1, bf);
    int idx = csr[__shfl(offv, 0) + lane];           // prefetch node 0
    for (int i = 0; i < 8; ++i) {
        int beg = __shfl(offv, i), end = __shfl(offv, i + 1);
        int cnt = end - beg;
        int idx_cur = idx;
        if (i < 7) idx = csr[end + lane];            // prefetch next node
        int node = nbase + i;
        float aLo, aHi;
        gather_node(y1, csr, idx_cur, beg, cnt, node, h, fp, lane, aLo, aHi);
        int mask = __shfl(maskv, i);
        float is = __shfl(isv, i);
#pragma unroll
        for (int t = 0; t < T_; ++t)
            if (mask & (1 << t)) { float2 pv = p1p[t * 32 + fp]; aLo += pv.x; aHi += pv.y; }
        float hLo = aLo * is + b1lo;
        float hHi = aHi * is + b1hi;
        hLo = (hLo >= 0.f) ? hLo : 0.01f * hLo;
        hHi = (hHi >= 0.f) ? hHi : 0.01f * hHi;
        if (h == 0) h1[(size_t)node * 32 + fp] = pack_bf2(hLo, hHi);
    }
}

// ---------------- h1 @ W2 via MFMA -> y2 (scaled by inv_s, bf16 packed) ----------------
__global__ __launch_bounds__(256) void k_gemm(const uint32_t* __restrict__ h1,
                                              const short8* __restrict__ Bfr2,
                                              const float* __restrict__ inv_s,
                                              uint32_t* __restrict__ y2) {
    int tid = threadIdx.x;
    int lane = tid & 63, wv = tid >> 6;
    int g = blockIdx.x & 63, c = blockIdx.x >> 6;   // c in [0,16)
    int row0 = g * N_ + c * 64 + wv * 16;
    int m = lane & 15, q = lane >> 4;
    const short8* ar = (const short8*)(h1 + (size_t)(row0 + m) * 32);
    short8 afr[2];
#pragma unroll
    for (int cc = 0; cc < 2; ++cc) afr[cc] = ar[cc * 4 + q];
    f32x4 acc[4] = {};
#pragma unroll
    for (int nt = 0; nt < 4; ++nt)
#pragma unroll
        for (int cc = 0; cc < 2; ++cc) {
            short8 bfr = Bfr2[(cc * 4 + nt) * 64 + lane];
            acc[nt] = __builtin_amdgcn_mfma_f32_16x16x32_bf16(afr[cc], bfr, acc[nt], 0, 0, 0);
        }
    float isv[4];
#pragma unroll
    for (int r = 0; r < 4; ++r) isv[r] = inv_s[row0 + q * 4 + r];
#pragma unroll
    for (int r = 0; r < 4; ++r) {
        int node = row0 + q * 4 + r;
#pragma unroll
        for (int nt = 0; nt < 4; ++nt) {
            float v = acc[nt][r] * isv[r];
            float vh = __shfl(v, lane + 1);
            if ((m & 1) == 0)
                y2[(size_t)node * 32 + nt * 8 + (m >> 1)] = pack_bf2(v, vh);
        }
    }
}

// ---------------- layer2: gather y2 + pooling epilogue ----------------
__global__ __launch_bounds__(256, 6) void k_layer2(const uint32_t* __restrict__ y2,
                                                   const float* __restrict__ inv_s,
                                                   const int* __restrict__ maskA,
                                                   const int* __restrict__ offs,
                                                   const int* __restrict__ csr,
                                                   const float* __restrict__ P2,
                                                   const void* __restrict__ b2,
                                                   const int* __restrict__ flag,
                                                   float* __restrict__ graph_sum) {
    __shared__ float2 p2p[T_ * 32];
    int bf = *flag;
    int tid = threadIdx.x;
    for (int i = tid; i < T_ * 32; i += 256) {
        int t = i >> 5, fp = i & 31;
        p2p[i] = make_float2(P2[t * H_ + 2 * fp], P2[t * H_ + 2 * fp + 1]);
    }
    __syncthreads();
    int lane = tid & 63, wv = tid >> 6;
    int h = lane >> 5, fp = lane & 31;
    int g = blockIdx.x & 63, c = blockIdx.x >> 6;   // c in [0,32)
    int nbase = g * N_ + c * 32 + wv * 8;
    int offv = offs[nbase + min(lane, 8)];
    float isv = inv_s[nbase + (lane & 7)];
    int maskv = maskA[nbase + (lane & 7)];
    float b2lo = ld1(b2, 2 * fp, bf), b2hi = ld1(b2, 2 * fp + 1, bf);
    int idx = csr[__shfl(offv, 0) + lane];
    float poolLo = 0.f, poolHi = 0.f;
    for (int i = 0; i < 8; ++i) {
        int beg = __shfl(offv, i), end = __shfl(offv, i + 1);
        int cnt = end - beg;
        int idx_cur = idx;
        if (i < 7) idx = csr[end + lane];
        int node = nbase + i;
        float aLo, aHi;
        gather_node(y2, csr, idx_cur, beg, cnt, node, h, fp, lane, aLo, aHi);
        int mask = __shfl(maskv, i);
        float is = __shfl(isv, i);
#pragma unroll
        for (int t = 0; t < T_; ++t)
            if (mask & (1 << t)) { float2 pv = p2p[t * 32 + fp]; aLo += pv.x; aHi += pv.y; }
        poolLo += aLo * is + b2lo;
        poolHi += aHi * is + b2hi;
    }
    if (h == 0) {
        atomicAdd(&graph_sum[g * H_ + 2 * fp], poolLo);
        atomicAdd(&graph_sum[g * H_ + 2 * fp + 1], poolHi);
    }
}

// ---------------- pooled emb -> answering head -> softmax ----------------
__global__ __launch_bounds__(64) void k_final(const float* __restrict__ graph_sum,
                                              const float* __restrict__ tok_sum,
                                              const void* __restrict__ Wa,
                                              const void* __restrict__ ba,
                                              const int* __restrict__ flag,
                                              void* __restrict__ out) {
    int bf = *flag;
    int b = blockIdx.x, l = threadIdx.x;
    float e = (tok_sum[l] + graph_sum[b * H_ + l]) * (1.0f / 1034.0f);
    float p0 = e * ld1(Wa, l * 2 + 0, bf);
    float p1 = e * ld1(Wa, l * 2 + 1, bf);
#pragma unroll
    for (int d = 32; d >= 1; d >>= 1) {
        p0 += __shfl_xor(p0, d);
        p1 += __shfl_xor(p1, d);
    }
    if (l == 0) {
        float l0 = p0 + ld1(ba, 0, bf);
        float l1 = p1 + ld1(ba, 1, bf);
        float mx = fmaxf(l0, l1);
        float e0 = expf(l0 - mx), e1 = expf(l1 - mx);
        float s = e0 + e1;
        float o0 = e0 / s, o1 = e1 / s;
        if (bf) {
            ((__hip_bfloat16*)out)[b * 2 + 0] = __float2bfloat16(o0);
            ((__hip_bfloat16*)out)[b * 2 + 1] = __float2bfloat16(o1);
        } else {
            ((float*)out)[b * 2 + 0] = o0;
            ((float*)out)[b * 2 + 1] = o1;
        }
    }
}

extern "C" void kernel_launch(void* const* d_in, const int* in_sizes, int n_in,
                              void* d_out, int out_size, void* d_ws, size_t ws_size,
                              hipStream_t stream) {
    (void)in_sizes; (void)n_in; (void)out_size; (void)ws_size;
    const void* x      = d_in[0];
    const void* tokens = d_in[1];
    const void* W1     = d_in[2];
    const void* b1     = d_in[3];
    const void* W2     = d_in[4];
    const void* b2     = d_in[5];
    const void* Wa     = d_in[6];
    const void* ba     = d_in[7];
    const int* esrc = (const int*)d_in[8];
    const int* edst = (const int*)d_in[9];

    char* w = (char*)d_ws;
    auto alloc = [&](size_t bytes) { void* p = (void*)w; w += (bytes + 255) & ~(size_t)255; return p; };
    int*      in_deg    = (int*)alloc(BN * 4);
    int*      offs      = (int*)alloc((BN + 1) * 4);
    int*      cursor    = (int*)alloc(BN * 4);
    int*      csr       = (int*)alloc(BE * 4 + 256);                   // +64-int pad for prefetch
    int*      maskA     = (int*)alloc(BN * 4);
    float*    inv_s     = (float*)alloc(BN * 4);
    uint32_t* y1        = (uint32_t*)alloc((size_t)(BN + 1) * 32 * 4); // packed bf16 pairs
    uint32_t* h1        = (uint32_t*)alloc((size_t)(BN + 1) * 32 * 4);
    uint32_t* y2        = (uint32_t*)alloc((size_t)(BN + 1) * 32 * 4);
    float*    P1        = (float*)alloc(T_ * H_ * 4);
    float*    P2        = (float*)alloc(T_ * H_ * 4);
    float*    tok_sum   = (float*)alloc(H_ * 4);
    float*    graph_sum = (float*)alloc(B_ * H_ * 4);
    short8*   Bfr       = (short8*)alloc(4 * 5 * 64 * sizeof(short8));
    short8*   Bfr2      = (short8*)alloc(2 * 4 * 64 * sizeof(short8));
    int*      dflag     = (int*)alloc(256);

    hipMemsetAsync(in_deg, 0, BN * 4, stream);
    hipMemsetAsync(graph_sum, 0, B_ * H_ * 4, stream);
    hipMemsetAsync(y1 + (size_t)BN * 32, 0, 128, stream);   // zero rows (gather padding)
    hipMemsetAsync(h1 + (size_t)BN * 32, 0, 128, stream);
    hipMemsetAsync(y2 + (size_t)BN * 32, 0, 128, stream);

    k_deg      <<<BE / 256, 256, 0, stream>>>(edst, in_deg);
    k_prep     <<<5, 256, 0, stream>>>(W1, tokens, dflag, Bfr);
    k_prep2    <<<2, 256, 0, stream>>>(W2, dflag, Bfr2);
    k_tok      <<<1, 64, 0, stream>>>(tokens, b1, b2, Bfr, Bfr2, dflag, P1, P2, tok_sum);
    k_scan     <<<1, 1024, 0, stream>>>(in_deg, offs, cursor);
    k_fill     <<<BE / 256, 256, 0, stream>>>(esrc, edst, cursor, csr);
    k_node_mfma<<<BN / 64, 256, 0, stream>>>(x, Bfr, in_deg, dflag, y1, inv_s, maskA);
    k_layer1   <<<BN / 32, 256, 0, stream>>>(y1, inv_s, maskA, offs, csr, P1, b1, dflag, h1);
    k_gemm     <<<BN / 64, 256, 0, stream>>>(h1, Bfr2, inv_s, y2);
    k_layer2   <<<BN / 32, 256, 0, stream>>>(y2, inv_s, maskA, offs, csr, P2, b2, dflag, graph_sum);
    k_final    <<<B_, 64, 0, stream>>>(graph_sum, tok_sum, Wa, ba, dflag, d_out);
}

// Round 7
// 215.276 us; speedup vs baseline: 3.5308x; 1.3332x over previous
//
#include <hip/hip_runtime.h>
#include <hip/hip_bf16.h>
#include <stdint.h>

#define B_ 64
#define N_ 1024
#define E_ 16384
#define F_ 128
#define H_ 64
#define T_ 10
#define BN (B_*N_)   // 65536
#define BE (B_*E_)   // 1048576
#define CAP 96       // bucket capacity per node (Poisson(16) in-degree; P(>96)~1e-40)

// sigmoid(z) >= p  <=>  z >= log(p/(1-p))
#define TH_INNER (-0.84729786f)   // logit(0.3)
#define TH_CROSS (-2.1972246f)    // logit(0.1)

typedef __attribute__((ext_vector_type(8))) short short8;  // bf16x8 MFMA frag
typedef __attribute__((ext_vector_type(4))) float f32x4;   // MFMA acc

// ---- dtype-agnostic loads: bf=1 -> packed bf16, bf=0 -> float32 ----
__device__ __forceinline__ float ld1(const void* p, int i, int bf) {
    if (bf) {
        uint16_t u = ((const uint16_t*)p)[i];
        return __uint_as_float(((uint32_t)u) << 16);
    }
    return ((const float*)p)[i];
}

__device__ __forceinline__ short to_bf(float x) {
    return (short)__bfloat16_as_ushort(__float2bfloat16(x));
}

__device__ __forceinline__ uint32_t pack_bf2(float lo, float hi) {
    uint32_t l = (uint32_t)__bfloat16_as_ushort(__float2bfloat16(lo));
    uint32_t h = (uint32_t)__bfloat16_as_ushort(__float2bfloat16(hi));
    return l | (h << 16);
}

__device__ __forceinline__ float bflo(uint32_t u) { return __uint_as_float(u << 16); }
__device__ __forceinline__ float bfhi(uint32_t u) { return __uint_as_float(u & 0xffff0000u); }

// ---------------- one-shot zero init (replaces 5 memsets) ----------------
__global__ __launch_bounds__(256) void k_init(int* __restrict__ cnt,
                                              float* __restrict__ gsum,
                                              uint32_t* __restrict__ y1pad,
                                              uint32_t* __restrict__ y2pad) {
    int b = blockIdx.x, t = threadIdx.x;
    if (b < 256) cnt[b * 256 + t] = 0;
    else if (b < 272) gsum[(b - 256) * 256 + t] = 0.f;
    else {
        if (t < 32) y1pad[t] = 0;
        else if (t < 64) y2pad[t - 32] = 0;
    }
}

// ---------------- single-pass bucketed edge scatter ----------------
__global__ __launch_bounds__(256) void k_bucket(const int* __restrict__ src,
                                                const int* __restrict__ dst,
                                                int* __restrict__ cnt,
                                                int* __restrict__ bucket) {
    int g = blockIdx.x & 63, chunk = blockIdx.x >> 6;    // XCD swizzle by graph
    int i = g * E_ + chunk * 256 + threadIdx.x;
    int d = g * N_ + dst[i];
    int p = atomicAdd(&cnt[d], 1);
    if (p < CAP) bucket[(size_t)d * CAP + p] = g * N_ + src[i];
}

// ---------------- B fragments (W1|tokens^T and W2) + publish dtype flag ----------------
__global__ __launch_bounds__(256) void k_prep(const void* __restrict__ W1,
                                              const void* __restrict__ W2,
                                              const void* __restrict__ tokens,
                                              int* __restrict__ flag,
                                              short8* __restrict__ Bfr,
                                              short8* __restrict__ Bfr2) {
    // local dtype detection (every block derives the same verdict)
    uint32_t du = ((const uint32_t*)tokens)[threadIdx.x & 63];
    float dlo = __uint_as_float(du << 16);
    unsigned long long vote = __ballot(fabsf(dlo) <= 1.0f);
    int bf = (vote == ~0ull) ? 1 : 0;
    if (blockIdx.x == 0 && threadIdx.x == 0) *flag = bf;

    int f = blockIdx.x * 256 + threadIdx.x;      // [0, 1792)
    if (f < 1280) {                              // Bfr: [128 x 80] = W1 | tokens^T
        int c = f / 320, rem = f % 320;
        int nt = rem / 64, lane = rem % 64;
        int q = lane >> 4, n = nt * 16 + (lane & 15);
        int k0 = c * 32 + q * 8;
        short8 v;
#pragma unroll
        for (int j = 0; j < 8; ++j) {
            int k = k0 + j;
            float x = 0.f;
            if (n < H_) x = ld1(W1, k * H_ + n, bf);
            else if (n < H_ + T_) x = ld1(tokens, (n - H_) * F_ + k, bf);
            v[j] = to_bf(x);
        }
        Bfr[f] = v;
    } else {                                     // Bfr2: W2 [64 x 64]
        int f2 = f - 1280;
        int c = f2 / 256, rem = f2 % 256;
        int nt = rem / 64, lane = rem % 64;
        int q = lane >> 4, n = nt * 16 + (lane & 15);
        int k0 = c * 32 + q * 8;
        short8 v;
#pragma unroll
        for (int j = 0; j < 8; ++j) v[j] = to_bf(ld1(W2, (k0 + j) * H_ + n, bf));
        Bfr2[f2] = v;
    }
}

// ---------------- token stream via MFMA (1 wave) ----------------
__global__ __launch_bounds__(64) void k_tok(const void* __restrict__ tokens,
                                            const void* __restrict__ b1,
                                            const void* __restrict__ b2,
                                            const short8* __restrict__ Bfr,
                                            const short8* __restrict__ Bfr2,
                                            const int* __restrict__ flag,
                                            float* __restrict__ P1,
                                            float* __restrict__ P2,
                                            float* __restrict__ tok_sum) {
    __shared__ float nm[T_ * 16];       // normMin[t][s] = Min*ist_t*ist_s
    __shared__ float ist_s[16], idt_s[16];
    __shared__ float htbuf[T_ * 64];    // ht1, later reused for ht2
    __shared__ float h1s[T_ * 64];
    int bf = *flag;
    int l = threadIdx.x;
    int m = l & 15, q = l >> 4;
    int mrow = (m < T_) ? m : (T_ - 1);          // clamp: rows >=10 masked later
    short8 afr[4];
    if (bf) {
        const short8* ar = (const short8*)((const uint16_t*)tokens + mrow * F_);
#pragma unroll
        for (int c = 0; c < 4; ++c) afr[c] = ar[c * 4 + q];
    } else {
        const float* ar = (const float*)tokens + mrow * F_;
#pragma unroll
        for (int c = 0; c < 4; ++c)
#pragma unroll
            for (int j = 0; j < 8; ++j) afr[c][j] = to_bf(ar[c * 32 + q * 8 + j]);
    }
    f32x4 accM = {};
    f32x4 acc1[4] = {};
#pragma unroll
    for (int c = 0; c < 4; ++c) {
        accM = __builtin_amdgcn_mfma_f32_16x16x32_bf16(afr[c], Bfr[(c * 5 + 4) * 64 + l], accM, 0, 0, 0);
#pragma unroll
        for (int nt = 0; nt < 4; ++nt)
            acc1[nt] = __builtin_amdgcn_mfma_f32_16x16x32_bf16(afr[c], Bfr[(c * 5 + nt) * 64 + l], acc1[nt], 0, 0, 0);
    }
    int cnt = 0;
#pragma unroll
    for (int r = 0; r < 4; ++r) {
        int row = q * 4 + r;
        if (row < T_ && m < T_ && accM[r] >= TH_INNER) cnt++;
    }
    cnt += __shfl_xor(cnt, 16);
    cnt += __shfl_xor(cnt, 32);
    float deg = 1.f + (float)cnt;
    float istc = 1.f / sqrtf(deg);
    float idtc = 1.f / deg;
    if (q == 0 && m < T_) { ist_s[m] = istc; idt_s[m] = idtc; }
#pragma unroll
    for (int nt = 0; nt < 4; ++nt)
#pragma unroll
        for (int r = 0; r < 4; ++r) {
            int row = q * 4 + r;
            if (row < T_) htbuf[row * 64 + nt * 16 + m] = acc1[nt][r];
        }
    __syncthreads();
    if (m < T_) {
#pragma unroll
        for (int r = 0; r < 4; ++r) {
            int row = q * 4 + r;
            if (row < T_)
                nm[row * 16 + m] = (accM[r] >= TH_INNER) ? ist_s[row] * istc : 0.f;
        }
    }
    __syncthreads();
    float htc[T_];
#pragma unroll
    for (int s = 0; s < T_; ++s) htc[s] = htbuf[s * 64 + l];
    float b1f = ld1(b1, l, bf);
#pragma unroll
    for (int t = 0; t < T_; ++t) {
        float a = htc[t] * idt_s[t] + b1f;
#pragma unroll
        for (int s = 0; s < T_; ++s) a += nm[t * 16 + s] * htc[s];
        a = (a >= 0.f) ? a : 0.01f * a;
        h1s[t * 64 + l] = a;
        P1[t * H_ + l] = ist_s[t] * htc[t];
    }
    __syncthreads();
    short8 a2fr[2];
#pragma unroll
    for (int c = 0; c < 2; ++c)
#pragma unroll
        for (int j = 0; j < 8; ++j) a2fr[c][j] = to_bf(h1s[mrow * 64 + c * 32 + q * 8 + j]);
    f32x4 acc2[4] = {};
#pragma unroll
    for (int nt = 0; nt < 4; ++nt)
#pragma unroll
        for (int c = 0; c < 2; ++c)
            acc2[nt] = __builtin_amdgcn_mfma_f32_16x16x32_bf16(a2fr[c], Bfr2[(c * 4 + nt) * 64 + l], acc2[nt], 0, 0, 0);
#pragma unroll
    for (int nt = 0; nt < 4; ++nt)
#pragma unroll
        for (int r = 0; r < 4; ++r) {
            int row = q * 4 + r;
            if (row < T_) htbuf[row * 64 + nt * 16 + m] = acc2[nt][r];
        }
    __syncthreads();
    float b2f = ld1(b2, l, bf);
#pragma unroll
    for (int s = 0; s < T_; ++s) htc[s] = htbuf[s * 64 + l];
    float ts = 0.f;
#pragma unroll
    for (int t = 0; t < T_; ++t) {
        float o = htc[t] * idt_s[t] + b2f;
#pragma unroll
        for (int s = 0; s < T_; ++s) o += nm[t * 16 + s] * htc[s];
        ts += o;
        P2[t * H_ + l] = ist_s[t] * htc[t];
    }
    tok_sum[l] = ts;
}

// ---------------- node GEMM via MFMA: y1(bf16 packed) + cross masks + inv_s ----------------
__global__ __launch_bounds__(256) void k_node_mfma(const void* __restrict__ x,
                                                   const short8* __restrict__ Bfr,
                                                   const int* __restrict__ cnt,
                                                   const int* __restrict__ flag,
                                                   uint32_t* __restrict__ y1,
                                                   float* __restrict__ inv_s,
                                                   int* __restrict__ maskA) {
    int bf = *flag;
    int tid = threadIdx.x;
    int lane = tid & 63, wv = tid >> 6;
    int g = blockIdx.x & 63, c = blockIdx.x >> 6;   // XCD swizzle
    int row0 = g * N_ + c * 64 + wv * 16;
    int m = lane & 15, q = lane >> 4;
    int row = row0 + m;
    short8 afr[4];
    if (bf) {
        const short8* ar = (const short8*)((const uint16_t*)x + (size_t)row * F_);
#pragma unroll
        for (int cc = 0; cc < 4; ++cc) afr[cc] = ar[cc * 4 + q];
    } else {
        const float* ar = (const float*)x + (size_t)row * F_;
#pragma unroll
        for (int cc = 0; cc < 4; ++cc)
#pragma unroll
            for (int j = 0; j < 8; ++j)
                afr[cc][j] = to_bf(ar[cc * 32 + q * 8 + j]);
    }
    f32x4 acc[5] = {};
#pragma unroll
    for (int nt = 0; nt < 5; ++nt)
#pragma unroll
        for (int cc = 0; cc < 4; ++cc) {
            short8 bfr = Bfr[(cc * 5 + nt) * 64 + lane];
            acc[nt] = __builtin_amdgcn_mfma_f32_16x16x32_bf16(afr[cc], bfr, acc[nt], 0, 0, 0);
        }
    unsigned long long bal[4];
#pragma unroll
    for (int r = 0; r < 4; ++r) {
        int pred = (m < T_) && (acc[4][r] >= TH_CROSS);
        bal[r] = __ballot(pred);
    }
    float isv[4];
#pragma unroll
    for (int r = 0; r < 4; ++r) {
        int node = row0 + q * 4 + r;
        int mask = (int)((bal[r] >> (q * 16)) & 0x3FF);
        float deg = 1.f + (float)cnt[node] + (float)__popc((unsigned)mask);
        isv[r] = 1.f / sqrtf(deg);
        if (m == 0) { inv_s[node] = isv[r]; maskA[node] = mask; }
    }
#pragma unroll
    for (int r = 0; r < 4; ++r) {
        int node = row0 + q * 4 + r;
#pragma unroll
        for (int nt = 0; nt < 4; ++nt) {
            float v = acc[nt][r] * isv[r];
            float vh = __shfl(v, lane + 1);
            if ((m & 1) == 0)
                y1[(size_t)node * 32 + nt * 8 + (m >> 1)] = pack_bf2(v, vh);
        }
    }
}

// ---------------- pair-domain gather from bucket rows, ILP=8 ----------------
__device__ __forceinline__ void gather_node(const uint32_t* __restrict__ yu,
                                            const int* __restrict__ brow,
                                            int idx_cur, int cnt,
                                            int node, int h, int fp, int lane,
                                            float& aLo, float& aHi) {
    float lo = 0.f, hi = 0.f;
    int eb = 0;
    while (true) {
        int cbat = min(cnt - eb, 64);
        int np = (cbat + 1) >> 1;
        for (int p = 0; p < np; p += 8) {
            int s[8];
#pragma unroll
            for (int j = 0; j < 8; ++j) {
                int e = 2 * (p + j) + h;
                int sv = __shfl(idx_cur, e & 63);
                s[j] = (e < cbat) ? sv : BN;     // BN = zero row
            }
            uint32_t u[8];
#pragma unroll
            for (int j = 0; j < 8; ++j) u[j] = yu[(size_t)s[j] * 32 + fp];
#pragma unroll
            for (int j = 0; j < 8; ++j) { lo += bflo(u[j]); hi += bfhi(u[j]); }
        }
        eb += 64;
        if (eb >= cnt) break;
        idx_cur = brow[eb + lane];               // rare (deg > 64)
    }
    lo += __shfl_xor(lo, 32);
    hi += __shfl_xor(hi, 32);
    uint32_t su = yu[(size_t)node * 32 + fp];    // self row
    aLo = lo + bflo(su);
    aHi = hi + bfhi(su);
}

// ---------------- layer1: gather y1 + epilogue + fused h1@W2 MFMA -> y2 ----------------
__global__ __launch_bounds__(256, 4) void k_layer1(const uint32_t* __restrict__ y1,
                                                   const float* __restrict__ inv_s,
                                                   const int* __restrict__ maskA,
                                                   const int* __restrict__ cnt,
                                                   const int* __restrict__ bucket,
                                                   const float* __restrict__ P1,
                                                   const void* __restrict__ b1,
                                                   const short8* __restrict__ Bfr2,
                                                   const int* __restrict__ flag,
                                                   uint32_t* __restrict__ y2) {
    __shared__ float2 p1p[T_ * 32];
    __shared__ uint32_t h1w[4][16 * 36];         // stride 36: 16B-aligned rows, 2-way-free banks
    int bf = *flag;
    int tid = threadIdx.x;
    for (int i = tid; i < T_ * 32; i += 256) {
        int t = i >> 5, fp = i & 31;
        p1p[i] = make_float2(P1[t * H_ + 2 * fp], P1[t * H_ + 2 * fp + 1]);
    }
    __syncthreads();
    int lane = tid & 63, wv = tid >> 6;
    int h = lane >> 5, fp = lane & 31;
    int g = blockIdx.x & 63, c = blockIdx.x >> 6;   // c in [0,16)
    int nbase = g * N_ + c * 64 + wv * 16;
    int cntv = min(cnt[nbase + (lane & 15)], CAP);
    float isv = inv_s[nbase + (lane & 15)];
    int maskv = maskA[nbase + (lane & 15)];
    float b1lo = ld1(b1, 2 * fp, bf), b1hi = ld1(b1, 2 * fp + 1, bf);
    int idx = bucket[(size_t)nbase * CAP + lane];    // prefetch node 0
    for (int i = 0; i < 16; ++i) {
        int node = nbase + i;
        int cnt_i = __shfl(cntv, i);
        int idx_cur = idx;
        if (i < 15) idx = bucket[(size_t)(node + 1) * CAP + lane];
        float aLo, aHi;
        gather_node(y1, bucket + (size_t)node * CAP, idx_cur, cnt_i, node, h, fp, lane, aLo, aHi);
        int mask = __shfl(maskv, i);
        float is = __shfl(isv, i);
#pragma unroll
        for (int t = 0; t < T_; ++t)
            if (mask & (1 << t)) { float2 pv = p1p[t * 32 + fp]; aLo += pv.x; aHi += pv.y; }
        float hLo = aLo * is + b1lo;
        float hHi = aHi * is + b1hi;
        hLo = (hLo >= 0.f) ? hLo : 0.01f * hLo;
        hHi = (hHi >= 0.f) ? hHi : 0.01f * hHi;
        if (h == 0) h1w[wv][i * 36 + fp] = pack_bf2(hLo, hHi);
    }
    // fused GEMM: y2 = (h1 @ W2) * inv_s   (wave-private LDS, wave-synchronous)
    int m = lane & 15, q = lane >> 4;
    short8 afr[2];
#pragma unroll
    for (int cc = 0; cc < 2; ++cc)
        afr[cc] = *(const short8*)&h1w[wv][m * 36 + cc * 16 + q * 4];
    f32x4 acc[4] = {};
#pragma unroll
    for (int nt = 0; nt < 4; ++nt)
#pragma unroll
        for (int cc = 0; cc < 2; ++cc)
            acc[nt] = __builtin_amdgcn_mfma_f32_16x16x32_bf16(afr[cc], Bfr2[(cc * 4 + nt) * 64 + lane], acc[nt], 0, 0, 0);
    float isr[4];
#pragma unroll
    for (int r = 0; r < 4; ++r) isr[r] = inv_s[nbase + q * 4 + r];
#pragma unroll
    for (int r = 0; r < 4; ++r) {
        int node = nbase + q * 4 + r;
#pragma unroll
        for (int nt = 0; nt < 4; ++nt) {
            float v = acc[nt][r] * isr[r];
            float vh = __shfl(v, lane + 1);
            if ((m & 1) == 0)
                y2[(size_t)node * 32 + nt * 8 + (m >> 1)] = pack_bf2(v, vh);
        }
    }
}

// ---------------- layer2: gather y2 + pooling epilogue ----------------
__global__ __launch_bounds__(256, 6) void k_layer2(const uint32_t* __restrict__ y2,
                                                   const float* __restrict__ inv_s,
                                                   const int* __restrict__ maskA,
                                                   const int* __restrict__ cnt,
                                                   const int* __restrict__ bucket,
                                                   const float* __restrict__ P2,
                                                   const void* __restrict__ b2,
                                                   const int* __restrict__ flag,
                                                   float* __restrict__ graph_sum) {
    __shared__ float2 p2p[T_ * 32];
    int bf = *flag;
    int tid = threadIdx.x;
    for (int i = tid; i < T_ * 32; i += 256) {
        int t = i >> 5, fp = i & 31;
        p2p[i] = make_float2(P2[t * H_ + 2 * fp], P2[t * H_ + 2 * fp + 1]);
    }
    __syncthreads();
    int lane = tid & 63, wv = tid >> 6;
    int h = lane >> 5, fp = lane & 31;
    int g = blockIdx.x & 63, c = blockIdx.x >> 6;   // c in [0,32)
    int nbase = g * N_ + c * 32 + wv * 8;
    int cntv = min(cnt[nbase + (lane & 7)], CAP);
    float isv = inv_s[nbase + (lane & 7)];
    int maskv = maskA[nbase + (lane & 7)];
    float b2lo = ld1(b2, 2 * fp, bf), b2hi = ld1(b2, 2 * fp + 1, bf);
    int idx = bucket[(size_t)nbase * CAP + lane];
    float poolLo = 0.f, poolHi = 0.f;
    for (int i = 0; i < 8; ++i) {
        int node = nbase + i;
        int cnt_i = __shfl(cntv, i);
        int idx_cur = idx;
        if (i < 7) idx = bucket[(size_t)(node + 1) * CAP + lane];
        float aLo, aHi;
        gather_node(y2, bucket + (size_t)node * CAP, idx_cur, cnt_i, node, h, fp, lane, aLo, aHi);
        int mask = __shfl(maskv, i);
        float is = __shfl(isv, i);
#pragma unroll
        for (int t = 0; t < T_; ++t)
            if (mask & (1 << t)) { float2 pv = p2p[t * 32 + fp]; aLo += pv.x; aHi += pv.y; }
        poolLo += aLo * is + b2lo;
        poolHi += aHi * is + b2hi;
    }
    if (h == 0) {
        atomicAdd(&graph_sum[g * H_ + 2 * fp], poolLo);
        atomicAdd(&graph_sum[g * H_ + 2 * fp + 1], poolHi);
    }
}

// ---------------- pooled emb -> answering head -> softmax ----------------
__global__ __launch_bounds__(64) void k_final(const float* __restrict__ graph_sum,
                                              const float* __restrict__ tok_sum,
                                              const void* __restrict__ Wa,
                                              const void* __restrict__ ba,
                                              const int* __restrict__ flag,
                                              void* __restrict__ out) {
    int bf = *flag;
    int b = blockIdx.x, l = threadIdx.x;
    float e = (tok_sum[l] + graph_sum[b * H_ + l]) * (1.0f / 1034.0f);
    float p0 = e * ld1(Wa, l * 2 + 0, bf);
    float p1 = e * ld1(Wa, l * 2 + 1, bf);
#pragma unroll
    for (int d = 32; d >= 1; d >>= 1) {
        p0 += __shfl_xor(p0, d);
        p1 += __shfl_xor(p1, d);
    }
    if (l == 0) {
        float l0 = p0 + ld1(ba, 0, bf);
        float l1 = p1 + ld1(ba, 1, bf);
        float mx = fmaxf(l0, l1);
        float e0 = expf(l0 - mx), e1 = expf(l1 - mx);
        float s = e0 + e1;
        float o0 = e0 / s, o1 = e1 / s;
        if (bf) {
            ((__hip_bfloat16*)out)[b * 2 + 0] = __float2bfloat16(o0);
            ((__hip_bfloat16*)out)[b * 2 + 1] = __float2bfloat16(o1);
        } else {
            ((float*)out)[b * 2 + 0] = o0;
            ((float*)out)[b * 2 + 1] = o1;
        }
    }
}

extern "C" void kernel_launch(void* const* d_in, const int* in_sizes, int n_in,
                              void* d_out, int out_size, void* d_ws, size_t ws_size,
                              hipStream_t stream) {
    (void)in_sizes; (void)n_in; (void)out_size; (void)ws_size;
    const void* x      = d_in[0];
    const void* tokens = d_in[1];
    const void* W1     = d_in[2];
    const void* b1     = d_in[3];
    const void* W2     = d_in[4];
    const void* b2     = d_in[5];
    const void* Wa     = d_in[6];
    const void* ba     = d_in[7];
    const int* esrc = (const int*)d_in[8];
    const int* edst = (const int*)d_in[9];

    char* w = (char*)d_ws;
    auto alloc = [&](size_t bytes) { void* p = (void*)w; w += (bytes + 255) & ~(size_t)255; return p; };
    int*      cnt       = (int*)alloc(BN * 4);
    int*      maskA     = (int*)alloc(BN * 4);
    float*    inv_s     = (float*)alloc(BN * 4);
    int*      bucket    = (int*)alloc((size_t)(BN + 1) * CAP * 4 + 256);
    uint32_t* y1        = (uint32_t*)alloc((size_t)(BN + 1) * 32 * 4); // packed bf16 pairs
    uint32_t* y2        = (uint32_t*)alloc((size_t)(BN + 1) * 32 * 4);
    float*    P1        = (float*)alloc(T_ * H_ * 4);
    float*    P2        = (float*)alloc(T_ * H_ * 4);
    float*    tok_sum   = (float*)alloc(H_ * 4);
    float*    graph_sum = (float*)alloc(B_ * H_ * 4);
    short8*   Bfr       = (short8*)alloc(4 * 5 * 64 * sizeof(short8));
    short8*   Bfr2      = (short8*)alloc(2 * 4 * 64 * sizeof(short8));
    int*      dflag     = (int*)alloc(256);

    k_init     <<<273, 256, 0, stream>>>(cnt, graph_sum, y1 + (size_t)BN * 32, y2 + (size_t)BN * 32);
    k_bucket   <<<BE / 256, 256, 0, stream>>>(esrc, edst, cnt, bucket);
    k_prep     <<<7, 256, 0, stream>>>(W1, W2, tokens, dflag, Bfr, Bfr2);
    k_tok      <<<1, 64, 0, stream>>>(tokens, b1, b2, Bfr, Bfr2, dflag, P1, P2, tok_sum);
    k_node_mfma<<<BN / 64, 256, 0, stream>>>(x, Bfr, cnt, dflag, y1, inv_s, maskA);
    k_layer1   <<<BN / 64, 256, 0, stream>>>(y1, inv_s, maskA, cnt, bucket, P1, b1, Bfr2, dflag, y2);
    k_layer2   <<<BN / 32, 256, 0, stream>>>(y2, inv_s, maskA, cnt, bucket, P2, b2, dflag, graph_sum);
    k_final    <<<B_, 64, 0, stream>>>(graph_sum, tok_sum, Wa, ba, dflag, d_out);
}

// Round 8
// 206.389 us; speedup vs baseline: 3.6828x; 1.0431x over previous
//
#include <hip/hip_runtime.h>
#include <hip/hip_bf16.h>
#include <stdint.h>

#define B_ 64
#define N_ 1024
#define E_ 16384
#define F_ 128
#define H_ 64
#define T_ 10
#define BN (B_*N_)   // 65536
#define BE (B_*E_)   // 1048576
#define CAP 96       // bucket capacity per node (edges + 10 token rows + self)

// sigmoid(z) >= p  <=>  z >= log(p/(1-p))
#define TH_INNER (-0.84729786f)   // logit(0.3)
#define TH_CROSS (-2.1972246f)    // logit(0.1)

typedef __attribute__((ext_vector_type(8))) short short8;  // bf16x8 MFMA frag
typedef __attribute__((ext_vector_type(4))) float f32x4;   // MFMA acc

__device__ __forceinline__ float ld1(const void* p, int i, int bf) {
    if (bf) {
        uint16_t u = ((const uint16_t*)p)[i];
        return __uint_as_float(((uint32_t)u) << 16);
    }
    return ((const float*)p)[i];
}

__device__ __forceinline__ short to_bf(float x) {
    return (short)__bfloat16_as_ushort(__float2bfloat16(x));
}

__device__ __forceinline__ uint32_t pack_bf2(float lo, float hi) {
    uint32_t l = (uint32_t)__bfloat16_as_ushort(__float2bfloat16(lo));
    uint32_t h = (uint32_t)__bfloat16_as_ushort(__float2bfloat16(hi));
    return l | (h << 16);
}

__device__ __forceinline__ float bflo(uint32_t u) { return __uint_as_float(u << 16); }
__device__ __forceinline__ float bfhi(uint32_t u) { return __uint_as_float(u & 0xffff0000u); }

// ---------------- one-shot zero init ----------------
__global__ __launch_bounds__(256) void k_init(int* __restrict__ cnt,
                                              float* __restrict__ gsum,
                                              uint32_t* __restrict__ y1pad,
                                              uint32_t* __restrict__ y2pad) {
    int b = blockIdx.x, t = threadIdx.x;
    if (b < 256) cnt[b * 256 + t] = 0;
    else if (b < 272) gsum[(b - 256) * 256 + t] = 0.f;
    else {
        if (t < 32) y1pad[t] = 0;
        else if (t < 64) y2pad[t - 32] = 0;
    }
}

// ---------------- single-pass bucketed edge scatter ----------------
__global__ __launch_bounds__(256) void k_bucket(const int* __restrict__ src,
                                                const int* __restrict__ dst,
                                                int* __restrict__ cnt,
                                                int* __restrict__ bucket) {
    int g = blockIdx.x & 63, chunk = blockIdx.x >> 6;    // XCD swizzle by graph
    int i = g * E_ + chunk * 256 + threadIdx.x;
    int d = g * N_ + dst[i];
    int p = atomicAdd(&cnt[d], 1);
    if (p < CAP - 11) bucket[(size_t)d * CAP + p] = g * N_ + src[i];
}

// ---------------- B fragments (W1|tokens^T and W2) + publish dtype flag ----------------
__global__ __launch_bounds__(256) void k_prep(const void* __restrict__ W1,
                                              const void* __restrict__ W2,
                                              const void* __restrict__ tokens,
                                              int* __restrict__ flag,
                                              short8* __restrict__ Bfr,
                                              short8* __restrict__ Bfr2) {
    uint32_t du = ((const uint32_t*)tokens)[threadIdx.x & 63];
    float dlo = __uint_as_float(du << 16);
    unsigned long long vote = __ballot(fabsf(dlo) <= 1.0f);
    int bf = (vote == ~0ull) ? 1 : 0;
    if (blockIdx.x == 0 && threadIdx.x == 0) *flag = bf;

    int f = blockIdx.x * 256 + threadIdx.x;      // [0, 1792)
    if (f < 1280) {                              // Bfr: [128 x 80] = W1 | tokens^T
        int c = f / 320, rem = f % 320;
        int nt = rem / 64, lane = rem % 64;
        int q = lane >> 4, n = nt * 16 + (lane & 15);
        int k0 = c * 32 + q * 8;
        short8 v;
#pragma unroll
        for (int j = 0; j < 8; ++j) {
            int k = k0 + j;
            float x = 0.f;
            if (n < H_) x = ld1(W1, k * H_ + n, bf);
            else if (n < H_ + T_) x = ld1(tokens, (n - H_) * F_ + k, bf);
            v[j] = to_bf(x);
        }
        Bfr[f] = v;
    } else {                                     // Bfr2: W2 [64 x 64]
        int f2 = f - 1280;
        int c = f2 / 256, rem = f2 % 256;
        int nt = rem / 64, lane = rem % 64;
        int q = lane >> 4, n = nt * 16 + (lane & 15);
        int k0 = c * 32 + q * 8;
        short8 v;
#pragma unroll
        for (int j = 0; j < 8; ++j) v[j] = to_bf(ld1(W2, (k0 + j) * H_ + n, bf));
        Bfr2[f2] = v;
    }
}

// ---------------- token stream via MFMA (1 wave); writes P rows into y1/y2 ----------------
__global__ __launch_bounds__(64) void k_tok(const void* __restrict__ tokens,
                                            const void* __restrict__ b1,
                                            const void* __restrict__ b2,
                                            const short8* __restrict__ Bfr,
                                            const short8* __restrict__ Bfr2,
                                            const int* __restrict__ flag,
                                            uint32_t* __restrict__ y1,
                                            uint32_t* __restrict__ y2,
                                            float* __restrict__ tok_sum) {
    __shared__ float nm[T_ * 16];       // normMin[t][s] = Min*ist_t*ist_s
    __shared__ float ist_s[16], idt_s[16];
    __shared__ float htbuf[T_ * 64];    // ht1, later reused for ht2
    __shared__ float h1s[T_ * 64];
    int bf = *flag;
    int l = threadIdx.x;
    int m = l & 15, q = l >> 4;
    int mrow = (m < T_) ? m : (T_ - 1);          // clamp: rows >=10 masked later
    short8 afr[4];
    if (bf) {
        const short8* ar = (const short8*)((const uint16_t*)tokens + mrow * F_);
#pragma unroll
        for (int c = 0; c < 4; ++c) afr[c] = ar[c * 4 + q];
    } else {
        const float* ar = (const float*)tokens + mrow * F_;
#pragma unroll
        for (int c = 0; c < 4; ++c)
#pragma unroll
            for (int j = 0; j < 8; ++j) afr[c][j] = to_bf(ar[c * 32 + q * 8 + j]);
    }
    f32x4 accM = {};
    f32x4 acc1[4] = {};
#pragma unroll
    for (int c = 0; c < 4; ++c) {
        accM = __builtin_amdgcn_mfma_f32_16x16x32_bf16(afr[c], Bfr[(c * 5 + 4) * 64 + l], accM, 0, 0, 0);
#pragma unroll
        for (int nt = 0; nt < 4; ++nt)
            acc1[nt] = __builtin_amdgcn_mfma_f32_16x16x32_bf16(afr[c], Bfr[(c * 5 + nt) * 64 + l], acc1[nt], 0, 0, 0);
    }
    int cnt = 0;
#pragma unroll
    for (int r = 0; r < 4; ++r) {
        int row = q * 4 + r;
        if (row < T_ && m < T_ && accM[r] >= TH_INNER) cnt++;
    }
    cnt += __shfl_xor(cnt, 16);
    cnt += __shfl_xor(cnt, 32);
    float deg = 1.f + (float)cnt;
    float istc = 1.f / sqrtf(deg);
    float idtc = 1.f / deg;
    if (q == 0 && m < T_) { ist_s[m] = istc; idt_s[m] = idtc; }
#pragma unroll
    for (int nt = 0; nt < 4; ++nt)
#pragma unroll
        for (int r = 0; r < 4; ++r) {
            int row = q * 4 + r;
            if (row < T_) htbuf[row * 64 + nt * 16 + m] = acc1[nt][r];
        }
    __syncthreads();
    if (m < T_) {
#pragma unroll
        for (int r = 0; r < 4; ++r) {
            int row = q * 4 + r;
            if (row < T_)
                nm[row * 16 + m] = (accM[r] >= TH_INNER) ? ist_s[row] * istc : 0.f;
        }
    }
    __syncthreads();
    float htc[T_];
#pragma unroll
    for (int s = 0; s < T_; ++s) htc[s] = htbuf[s * 64 + l];
    float b1f = ld1(b1, l, bf);
#pragma unroll
    for (int t = 0; t < T_; ++t) {
        float a = htc[t] * idt_s[t] + b1f;
#pragma unroll
        for (int s = 0; s < T_; ++s) a += nm[t * 16 + s] * htc[s];
        a = (a >= 0.f) ? a : 0.01f * a;
        h1s[t * 64 + l] = a;
        float v = ist_s[t] * htc[t];              // P1 row -> y1[BN+1+t]
        float vh = __shfl(v, l + 1);
        if ((l & 1) == 0) y1[(size_t)(BN + 1 + t) * 32 + (l >> 1)] = pack_bf2(v, vh);
    }
    __syncthreads();
    short8 a2fr[2];
#pragma unroll
    for (int c = 0; c < 2; ++c)
#pragma unroll
        for (int j = 0; j < 8; ++j) a2fr[c][j] = to_bf(h1s[mrow * 64 + c * 32 + q * 8 + j]);
    f32x4 acc2[4] = {};
#pragma unroll
    for (int nt = 0; nt < 4; ++nt)
#pragma unroll
        for (int c = 0; c < 2; ++c)
            acc2[nt] = __builtin_amdgcn_mfma_f32_16x16x32_bf16(a2fr[c], Bfr2[(c * 4 + nt) * 64 + l], acc2[nt], 0, 0, 0);
#pragma unroll
    for (int nt = 0; nt < 4; ++nt)
#pragma unroll
        for (int r = 0; r < 4; ++r) {
            int row = q * 4 + r;
            if (row < T_) htbuf[row * 64 + nt * 16 + m] = acc2[nt][r];
        }
    __syncthreads();
    float b2f = ld1(b2, l, bf);
#pragma unroll
    for (int s = 0; s < T_; ++s) htc[s] = htbuf[s * 64 + l];
    float ts = 0.f;
#pragma unroll
    for (int t = 0; t < T_; ++t) {
        float o = htc[t] * idt_s[t] + b2f;
#pragma unroll
        for (int s = 0; s < T_; ++s) o += nm[t * 16 + s] * htc[s];
        ts += o;
        float v = ist_s[t] * htc[t];              // P2 row -> y2[BN+1+t]
        float vh = __shfl(v, l + 1);
        if ((l & 1) == 0) y2[(size_t)(BN + 1 + t) * 32 + (l >> 1)] = pack_bf2(v, vh);
    }
    tok_sum[l] = ts;
}

// ---------------- node GEMM: y1 + virtual-edge append + cnt2 + inv_s ----------------
__global__ __launch_bounds__(256) void k_node_mfma(const void* __restrict__ x,
                                                   const short8* __restrict__ Bfr,
                                                   const int* __restrict__ cnt,
                                                   const int* __restrict__ flag,
                                                   uint32_t* __restrict__ y1,
                                                   float* __restrict__ inv_s,
                                                   int* __restrict__ cnt2,
                                                   int* __restrict__ bucket) {
    int bf = *flag;
    int tid = threadIdx.x;
    int lane = tid & 63, wv = tid >> 6;
    int g = blockIdx.x & 63, c = blockIdx.x >> 6;   // XCD swizzle
    int row0 = g * N_ + c * 64 + wv * 16;
    int m = lane & 15, q = lane >> 4;
    int row = row0 + m;
    short8 afr[4];
    if (bf) {
        const short8* ar = (const short8*)((const uint16_t*)x + (size_t)row * F_);
#pragma unroll
        for (int cc = 0; cc < 4; ++cc) afr[cc] = ar[cc * 4 + q];
    } else {
        const float* ar = (const float*)x + (size_t)row * F_;
#pragma unroll
        for (int cc = 0; cc < 4; ++cc)
#pragma unroll
            for (int j = 0; j < 8; ++j)
                afr[cc][j] = to_bf(ar[cc * 32 + q * 8 + j]);
    }
    f32x4 acc[5] = {};
#pragma unroll
    for (int nt = 0; nt < 5; ++nt)
#pragma unroll
        for (int cc = 0; cc < 4; ++cc) {
            short8 bfr = Bfr[(cc * 5 + nt) * 64 + lane];
            acc[nt] = __builtin_amdgcn_mfma_f32_16x16x32_bf16(afr[cc], bfr, acc[nt], 0, 0, 0);
        }
    unsigned long long bal[4];
#pragma unroll
    for (int r = 0; r < 4; ++r) {
        int pred = (m < T_) && (acc[4][r] >= TH_CROSS);
        bal[r] = __ballot(pred);
    }
    float isv[4];
#pragma unroll
    for (int r = 0; r < 4; ++r) {
        int node = row0 + q * 4 + r;
        int mask = (int)((bal[r] >> (q * 16)) & 0x3FF);
        int ec = cnt[node];
        int pc = __popc((unsigned)mask);
        float deg = 1.f + (float)ec + (float)pc;
        isv[r] = 1.f / sqrtf(deg);
        int base = min(ec, CAP - 11);
        // virtual-edge append: token rows + self (parallel across m-lanes)
        if (m < T_ && ((mask >> m) & 1))
            bucket[(size_t)node * CAP + base + __popc((unsigned)(mask & ((1 << m) - 1)))] = BN + 1 + m;
        if (m == 10) bucket[(size_t)node * CAP + base + pc] = node;
        if (m == 0) { inv_s[node] = isv[r]; cnt2[node] = base + pc + 1; }
    }
#pragma unroll
    for (int r = 0; r < 4; ++r) {
        int node = row0 + q * 4 + r;
#pragma unroll
        for (int nt = 0; nt < 4; ++nt) {
            float v = acc[nt][r] * isv[r];
            float vh = __shfl(v, lane + 1);
            if ((m & 1) == 0)
                y1[(size_t)node * 32 + nt * 8 + (m >> 1)] = pack_bf2(v, vh);
        }
    }
}

// ---------------- dwordx2 gather: 4 rows/load, J=8 covers 32 edge-slots ----------------
// lane l: row-slot r4 = l>>4, words 2*(l&15), 2*(l&15)+1 of each row.
// Returns full sums (all lanes) of features 4*(l&15) .. 4*(l&15)+3.
__device__ __forceinline__ void gather4(const uint32_t* __restrict__ yu,
                                        const int* __restrict__ brow,
                                        int idx_cur, int cnt, int lane,
                                        float& lo0, float& hi0, float& lo1, float& hi1) {
    lo0 = hi0 = lo1 = hi1 = 0.f;
    int r4 = lane >> 4, wp = lane & 15;
    int eb = 0;
    while (true) {
        int cbat = min(cnt - eb, 64);
        for (int half = 0; half < 64; half += 32) {
            if (half >= cbat) break;
            int s[8];
#pragma unroll
            for (int j = 0; j < 8; ++j) {
                int e = half + 4 * j + r4;
                int sv = __shfl(idx_cur, e & 63);
                s[j] = (e < cbat) ? sv : BN;     // BN = zero row
            }
            uint2 u[8];
#pragma unroll
            for (int j = 0; j < 8; ++j)
                u[j] = ((const uint2*)(yu + (size_t)s[j] * 32))[wp];
#pragma unroll
            for (int j = 0; j < 8; ++j) {
                lo0 += bflo(u[j].x); hi0 += bfhi(u[j].x);
                lo1 += bflo(u[j].y); hi1 += bfhi(u[j].y);
            }
        }
        eb += 64;
        if (eb >= cnt) break;
        idx_cur = brow[eb + lane];               // rare (cnt > 64)
    }
    lo0 += __shfl_xor(lo0, 16); hi0 += __shfl_xor(hi0, 16);
    lo1 += __shfl_xor(lo1, 16); hi1 += __shfl_xor(hi1, 16);
    lo0 += __shfl_xor(lo0, 32); hi0 += __shfl_xor(hi0, 32);
    lo1 += __shfl_xor(lo1, 32); hi1 += __shfl_xor(hi1, 32);
}

// ---------------- layer1: pure bucket gather + epilogue + fused h1@W2 -> y2 ----------------
__global__ __launch_bounds__(256, 4) void k_layer1(const uint32_t* __restrict__ y1,
                                                   const float* __restrict__ inv_s,
                                                   const int* __restrict__ cnt2,
                                                   const int* __restrict__ bucket,
                                                   const void* __restrict__ b1,
                                                   const short8* __restrict__ Bfr2,
                                                   const int* __restrict__ flag,
                                                   uint32_t* __restrict__ y2) {
    __shared__ uint32_t h1w[4][16 * 36];         // wave-private h1, stride 36 words
    int bf = *flag;
    int tid = threadIdx.x;
    int lane = tid & 63, wv = tid >> 6;
    int wp = lane & 15;
    int g = blockIdx.x & 63, c = blockIdx.x >> 6;   // c in [0,16)
    int nbase = g * N_ + c * 64 + wv * 16;
    int cntv = cnt2[nbase + wp];
    float isv = inv_s[nbase + wp];
    float bL0 = ld1(b1, 4 * wp + 0, bf), bH0 = ld1(b1, 4 * wp + 1, bf);
    float bL1 = ld1(b1, 4 * wp + 2, bf), bH1 = ld1(b1, 4 * wp + 3, bf);
    int idx = bucket[(size_t)nbase * CAP + lane];    // prefetch node 0
    for (int i = 0; i < 16; ++i) {
        int node = nbase + i;
        int cnt_i = __shfl(cntv, i);
        int idx_cur = idx;
        if (i < 15) idx = bucket[(size_t)(node + 1) * CAP + lane];
        float lo0, hi0, lo1, hi1;
        gather4(y1, bucket + (size_t)node * CAP, idx_cur, cnt_i, lane, lo0, hi0, lo1, hi1);
        float is = __shfl(isv, i);
        float h0 = lo0 * is + bL0, h1v = hi0 * is + bH0;
        float h2 = lo1 * is + bL1, h3 = hi1 * is + bH1;
        h0 = (h0 >= 0.f) ? h0 : 0.01f * h0;
        h1v = (h1v >= 0.f) ? h1v : 0.01f * h1v;
        h2 = (h2 >= 0.f) ? h2 : 0.01f * h2;
        h3 = (h3 >= 0.f) ? h3 : 0.01f * h3;
        if (lane < 16) {
            h1w[wv][i * 36 + 2 * wp] = pack_bf2(h0, h1v);
            h1w[wv][i * 36 + 2 * wp + 1] = pack_bf2(h2, h3);
        }
    }
    // fused GEMM: y2 = (h1 @ W2) * inv_s (wave-synchronous)
    int m = lane & 15, q = lane >> 4;
    short8 afr[2];
#pragma unroll
    for (int cc = 0; cc < 2; ++cc)
        afr[cc] = *(const short8*)&h1w[wv][m * 36 + cc * 16 + q * 4];
    f32x4 acc[4] = {};
#pragma unroll
    for (int nt = 0; nt < 4; ++nt)
#pragma unroll
        for (int cc = 0; cc < 2; ++cc)
            acc[nt] = __builtin_amdgcn_mfma_f32_16x16x32_bf16(afr[cc], Bfr2[(cc * 4 + nt) * 64 + lane], acc[nt], 0, 0, 0);
    float isr[4];
#pragma unroll
    for (int r = 0; r < 4; ++r) isr[r] = inv_s[nbase + q * 4 + r];
#pragma unroll
    for (int r = 0; r < 4; ++r) {
        int node = nbase + q * 4 + r;
#pragma unroll
        for (int nt = 0; nt < 4; ++nt) {
            float v = acc[nt][r] * isr[r];
            float vh = __shfl(v, lane + 1);
            if ((m & 1) == 0)
                y2[(size_t)node * 32 + nt * 8 + (m >> 1)] = pack_bf2(v, vh);
        }
    }
}

// ---------------- layer2: pure bucket gather + pooling ----------------
__global__ __launch_bounds__(256, 6) void k_layer2(const uint32_t* __restrict__ y2,
                                                   const float* __restrict__ inv_s,
                                                   const int* __restrict__ cnt2,
                                                   const int* __restrict__ bucket,
                                                   const void* __restrict__ b2,
                                                   const int* __restrict__ flag,
                                                   float* __restrict__ graph_sum) {
    int bf = *flag;
    int tid = threadIdx.x;
    int lane = tid & 63, wv = tid >> 6;
    int wp = lane & 15;
    int g = blockIdx.x & 63, c = blockIdx.x >> 6;   // c in [0,32)
    int nbase = g * N_ + c * 32 + wv * 8;
    int cntv = cnt2[nbase + (lane & 7)];
    float isv = inv_s[nbase + (lane & 7)];
    float bL0 = ld1(b2, 4 * wp + 0, bf), bH0 = ld1(b2, 4 * wp + 1, bf);
    float bL1 = ld1(b2, 4 * wp + 2, bf), bH1 = ld1(b2, 4 * wp + 3, bf);
    int idx = bucket[(size_t)nbase * CAP + lane];
    float p0 = 0.f, p1 = 0.f, p2 = 0.f, p3 = 0.f;
    for (int i = 0; i < 8; ++i) {
        int node = nbase + i;
        int cnt_i = __shfl(cntv, i);
        int idx_cur = idx;
        if (i < 7) idx = bucket[(size_t)(node + 1) * CAP + lane];
        float lo0, hi0, lo1, hi1;
        gather4(y2, bucket + (size_t)node * CAP, idx_cur, cnt_i, lane, lo0, hi0, lo1, hi1);
        float is = __shfl(isv, i);
        p0 += lo0 * is + bL0;
        p1 += hi0 * is + bH0;
        p2 += lo1 * is + bL1;
        p3 += hi1 * is + bH1;
    }
    if (lane < 16) {
        atomicAdd(&graph_sum[g * H_ + 4 * wp + 0], p0);
        atomicAdd(&graph_sum[g * H_ + 4 * wp + 1], p1);
        atomicAdd(&graph_sum[g * H_ + 4 * wp + 2], p2);
        atomicAdd(&graph_sum[g * H_ + 4 * wp + 3], p3);
    }
}

// ---------------- pooled emb -> answering head -> softmax ----------------
__global__ __launch_bounds__(64) void k_final(const float* __restrict__ graph_sum,
                                              const float* __restrict__ tok_sum,
                                              const void* __restrict__ Wa,
                                              const void* __restrict__ ba,
                                              const int* __restrict__ flag,
                                              void* __restrict__ out) {
    int bf = *flag;
    int b = blockIdx.x, l = threadIdx.x;
    float e = (tok_sum[l] + graph_sum[b * H_ + l]) * (1.0f / 1034.0f);
    float p0 = e * ld1(Wa, l * 2 + 0, bf);
    float p1 = e * ld1(Wa, l * 2 + 1, bf);
#pragma unroll
    for (int d = 32; d >= 1; d >>= 1) {
        p0 += __shfl_xor(p0, d);
        p1 += __shfl_xor(p1, d);
    }
    if (l == 0) {
        float l0 = p0 + ld1(ba, 0, bf);
        float l1 = p1 + ld1(ba, 1, bf);
        float mx = fmaxf(l0, l1);
        float e0 = expf(l0 - mx), e1 = expf(l1 - mx);
        float s = e0 + e1;
        float o0 = e0 / s, o1 = e1 / s;
        if (bf) {
            ((__hip_bfloat16*)out)[b * 2 + 0] = __float2bfloat16(o0);
            ((__hip_bfloat16*)out)[b * 2 + 1] = __float2bfloat16(o1);
        } else {
            ((float*)out)[b * 2 + 0] = o0;
            ((float*)out)[b * 2 + 1] = o1;
        }
    }
}

extern "C" void kernel_launch(void* const* d_in, const int* in_sizes, int n_in,
                              void* d_out, int out_size, void* d_ws, size_t ws_size,
                              hipStream_t stream) {
    (void)in_sizes; (void)n_in; (void)out_size; (void)ws_size;
    const void* x      = d_in[0];
    const void* tokens = d_in[1];
    const void* W1     = d_in[2];
    const void* b1     = d_in[3];
    const void* W2     = d_in[4];
    const void* b2     = d_in[5];
    const void* Wa     = d_in[6];
    const void* ba     = d_in[7];
    const int* esrc = (const int*)d_in[8];
    const int* edst = (const int*)d_in[9];

    char* w = (char*)d_ws;
    auto alloc = [&](size_t bytes) { void* p = (void*)w; w += (bytes + 255) & ~(size_t)255; return p; };
    int*      cnt       = (int*)alloc(BN * 4);
    int*      cnt2      = (int*)alloc(BN * 4);
    float*    inv_s     = (float*)alloc(BN * 4);
    int*      bucket    = (int*)alloc((size_t)(BN + 1) * CAP * 4 + 512);
    uint32_t* y1        = (uint32_t*)alloc((size_t)(BN + 12) * 32 * 4); // node rows + pad row BN + P rows BN+1..BN+10
    uint32_t* y2        = (uint32_t*)alloc((size_t)(BN + 12) * 32 * 4);
    float*    tok_sum   = (float*)alloc(H_ * 4);
    float*    graph_sum = (float*)alloc(B_ * H_ * 4);
    short8*   Bfr       = (short8*)alloc(4 * 5 * 64 * sizeof(short8));
    short8*   Bfr2      = (short8*)alloc(2 * 4 * 64 * sizeof(short8));
    int*      dflag     = (int*)alloc(256);

    k_init     <<<273, 256, 0, stream>>>(cnt, graph_sum, y1 + (size_t)BN * 32, y2 + (size_t)BN * 32);
    k_bucket   <<<BE / 256, 256, 0, stream>>>(esrc, edst, cnt, bucket);
    k_prep     <<<7, 256, 0, stream>>>(W1, W2, tokens, dflag, Bfr, Bfr2);
    k_tok      <<<1, 64, 0, stream>>>(tokens, b1, b2, Bfr, Bfr2, dflag, y1, y2, tok_sum);
    k_node_mfma<<<BN / 64, 256, 0, stream>>>(x, Bfr, cnt, dflag, y1, inv_s, cnt2, bucket);
    k_layer1   <<<BN / 64, 256, 0, stream>>>(y1, inv_s, cnt2, bucket, b1, Bfr2, dflag, y2);
    k_layer2   <<<BN / 32, 256, 0, stream>>>(y2, inv_s, cnt2, bucket, b2, dflag, graph_sum);
    k_final    <<<B_, 64, 0, stream>>>(graph_sum, tok_sum, Wa, ba, dflag, d_out);
}